// Round 3
// baseline (689.856 us; speedup 1.0000x reference)
//
#include <hip/hip_runtime.h>

static constexpr int F = 128;
static constexpr int N_RBF = 20;
static constexpr int N_ATOMS = 8000;
static constexpr int NP = 8064;          // N_ATOMS padded to 128 (pad rows: harness poison = tiny normal floats, benign)
static constexpr int N_EDGES = 160000;
static constexpr int N_MOLS = 100;
static constexpr float CUTOFF = 5.0f;
#define PIF 3.14159265358979323846f

__device__ __forceinline__ float silu_f(float x) { return x / (1.f + __expf(-x)); }

// ---------------- edge geometry + live-edge histogram ----------------
__global__ __launch_bounds__(256) void geom_kernel(
    const float* __restrict__ xyz, const int* __restrict__ nbrs,
    float* __restrict__ rbfe, float* __restrict__ envb, float* __restrict__ unitb,
    int* __restrict__ cnt)
{
    int e = blockIdx.x * 256 + threadIdx.x;
    if (e >= N_EDGES) return;
    int i0 = nbrs[2*e+0], i1 = nbrs[2*e+1];
    float dx = xyz[3*i1+0] - xyz[3*i0+0];
    float dy = xyz[3*i1+1] - xyz[3*i0+1];
    float dz = xyz[3*i1+2] - xyz[3*i0+2];
    float d  = sqrtf(dx*dx + dy*dy + dz*dz);
    float inv = 1.f / d;
    unitb[3*e+0] = dx*inv; unitb[3*e+1] = dy*inv; unitb[3*e+2] = dz*inv;
    float ev = (d <= CUTOFF) ? 0.5f*(cosf(PIF*d/CUTOFF) + 1.f) : 0.f;
    envb[e] = ev;
    float base = PIF*d/CUTOFF;
    float sc = inv * ev;   // fold env into rbf (w_s = (rbf*env)@W + b*env)
    #pragma unroll
    for (int k = 0; k < N_RBF; ++k)
        rbfe[e*N_RBF + k] = sinf((float)(k+1)*base) * sc;
    if (ev > 0.f) atomicAdd(&cnt[i0], 1);   // live-edge histogram by target
}

// ---------------- exclusive scan of 8000 counters (single block) ----------------
__global__ __launch_bounds__(1024) void scan_kernel(
    const int* __restrict__ cnt, int* __restrict__ offsets)
{
    __shared__ int sums[1024];
    int tid = threadIdx.x;
    int base = tid * 8;
    int local[8]; int s = 0;
    #pragma unroll
    for (int i = 0; i < 8; ++i) {
        int idx = base + i;
        local[i] = (idx < N_ATOMS) ? cnt[idx] : 0;
        s += local[i];
    }
    sums[tid] = s;
    __syncthreads();
    for (int d = 1; d < 1024; d <<= 1) {
        int v = (tid >= d) ? sums[tid - d] : 0;
        __syncthreads();
        sums[tid] += v;
        __syncthreads();
    }
    int ex = (tid == 0) ? 0 : sums[tid - 1];
    #pragma unroll
    for (int i = 0; i < 8; ++i) {
        int idx = base + i;
        if (idx < N_ATOMS) { offsets[idx] = ex; ex += local[i]; }
    }
}

// ---------------- scatter live edge ids into per-atom segments ----------------
__global__ __launch_bounds__(256) void scatter_kernel(
    const int* __restrict__ nbrs, const float* __restrict__ envb,
    const int* __restrict__ offsets, int* __restrict__ cursor,
    int* __restrict__ sorted_eid)
{
    int e = blockIdx.x * 256 + threadIdx.x;
    if (e >= N_EDGES) return;
    if (envb[e] <= 0.f) return;
    int tgt = nbrs[2*e+0];
    int pos = offsets[tgt] + atomicAdd(&cursor[tgt], 1);
    sorted_eid[pos] = e;
}

// ---------------- s = emb_table[z] ----------------
__global__ __launch_bounds__(256) void embed_kernel(
    const float* __restrict__ emb, const int* __restrict__ z, float* __restrict__ s)
{
    int idx = blockIdx.x * 256 + threadIdx.x;   // grid sized exactly N_ATOMS*F
    int n = idx >> 7, f = idx & 127;
    s[idx] = emb[z[n]*F + f];
}

// ---------------- big-tile f32 GEMM: C = act(A@B + bias) ----------------
// TM x 128 tile, 256 threads, 8x8 (TM=128) or 4x8 (TM=64) per-thread blocking.
// A: MxK row-major, B: KxNc row-major. M%TM==0, Nc%128==0, K%32==0.
// Fragment reads are two stride-4 float4s per operand -> 2-way bank aliasing (free).
template<int TM>
__global__ __launch_bounds__(256) void gemm_big(
    const float* __restrict__ A, const float* __restrict__ B,
    const float* __restrict__ bias, float* __restrict__ C,
    int K, int Nc, int act)
{
    constexpr int TN = 128;
    constexpr int BK = 32;
    constexpr int MR = TM / 64;            // 1 or 2
    __shared__ float As[BK][TM + 4];       // [k][m]
    __shared__ float Bs[BK][TN + 4];       // [k][n]
    const int tid = threadIdx.x;
    const int tx = tid & 15, ty = tid >> 4;
    const int m0 = blockIdx.y * TM, n0 = blockIdx.x * TN;
    float acc[MR * 4][8];
    #pragma unroll
    for (int i = 0; i < MR * 4; ++i)
        #pragma unroll
        for (int j = 0; j < 8; ++j) acc[i][j] = 0.f;

    const int kqa = tid & 7;               // float4-col within BK (A load)
    const int ra  = tid >> 3;              // 32 rows per pass  (A load)
    const int cb  = (tid & 31) * 4;        // B col
    const int kb  = tid >> 5;              // B row, 8 per pass

    for (int k0 = 0; k0 < K; k0 += BK) {
        #pragma unroll
        for (int p = 0; p < TM / 32; ++p) {
            float4 av = *(const float4*)&A[(size_t)(m0 + ra + 32 * p) * K + k0 + kqa * 4];
            As[kqa * 4 + 0][ra + 32 * p] = av.x;
            As[kqa * 4 + 1][ra + 32 * p] = av.y;
            As[kqa * 4 + 2][ra + 32 * p] = av.z;
            As[kqa * 4 + 3][ra + 32 * p] = av.w;
        }
        #pragma unroll
        for (int p = 0; p < 4; ++p)
            *(float4*)&Bs[kb + 8 * p][cb] = *(const float4*)&B[(size_t)(k0 + kb + 8 * p) * Nc + n0 + cb];
        __syncthreads();
        #pragma unroll
        for (int kk = 0; kk < BK; ++kk) {
            float4 b0 = *(const float4*)&Bs[kk][tx * 4];
            float4 b1 = *(const float4*)&Bs[kk][64 + tx * 4];
            float bb[8] = {b0.x, b0.y, b0.z, b0.w, b1.x, b1.y, b1.z, b1.w};
            #pragma unroll
            for (int h = 0; h < MR; ++h) {
                float4 a = *(const float4*)&As[kk][64 * h + ty * 4];
                float aa[4] = {a.x, a.y, a.z, a.w};
                #pragma unroll
                for (int i = 0; i < 4; ++i)
                    #pragma unroll
                    for (int j = 0; j < 8; ++j)
                        acc[h * 4 + i][j] += aa[i] * bb[j];
            }
        }
        __syncthreads();
    }
    float bcol[8];
    #pragma unroll
    for (int j = 0; j < 8; ++j) {
        int col = n0 + (j < 4 ? tx * 4 + j : 64 + tx * 4 + j - 4);
        bcol[j] = bias ? bias[col] : 0.f;
    }
    #pragma unroll
    for (int h = 0; h < MR; ++h) {
        #pragma unroll
        for (int i = 0; i < 4; ++i) {
            int row = m0 + 64 * h + ty * 4 + i;
            float4 o0, o1;
            o0.x = acc[h*4+i][0] + bcol[0]; o0.y = acc[h*4+i][1] + bcol[1];
            o0.z = acc[h*4+i][2] + bcol[2]; o0.w = acc[h*4+i][3] + bcol[3];
            o1.x = acc[h*4+i][4] + bcol[4]; o1.y = acc[h*4+i][5] + bcol[5];
            o1.z = acc[h*4+i][6] + bcol[6]; o1.w = acc[h*4+i][7] + bcol[7];
            if (act) {
                o0.x = silu_f(o0.x); o0.y = silu_f(o0.y); o0.z = silu_f(o0.z); o0.w = silu_f(o0.w);
                o1.x = silu_f(o1.x); o1.y = silu_f(o1.y); o1.z = silu_f(o1.z); o1.w = silu_f(o1.w);
            }
            *(float4*)&C[(size_t)row * Nc + n0 + tx * 4]      = o0;
            *(float4*)&C[(size_t)row * Nc + n0 + 64 + tx * 4] = o1;
        }
    }
}

// ---------------- small GEMM (readout only): 64x64 tile, 4x4 ----------------
__global__ __launch_bounds__(256) void gemm_bias_act(
    const float* __restrict__ A, const float* __restrict__ B,
    const float* __restrict__ bias, float* __restrict__ C,
    int M, int K, int Nc, int act)
{
    __shared__ float As[16][68];
    __shared__ float Bs[16][64];
    const int tid = threadIdx.x;
    const int tx = tid & 15, ty = tid >> 4;
    const int m0 = blockIdx.y * 64, n0 = blockIdx.x * 64;
    float acc[4][4] = {};
    const int ka = tid & 15;
    const int ma = tid >> 4;
    const int kb = tid >> 4;
    const int cb = (tid & 15) * 4;
    for (int k0 = 0; k0 < K; k0 += 16) {
        #pragma unroll
        for (int r = 0; r < 4; ++r)
            As[ka][ma + 16*r] = A[(size_t)(m0 + ma + 16*r) * K + k0 + ka];
        *(float4*)&Bs[kb][cb] = *(const float4*)&B[(size_t)(k0 + kb) * Nc + n0 + cb];
        __syncthreads();
        #pragma unroll
        for (int kk = 0; kk < 16; ++kk) {
            float4 av = *(const float4*)&As[kk][ty*4];
            float4 bv = *(const float4*)&Bs[kk][tx*4];
            float aa[4] = {av.x, av.y, av.z, av.w};
            float bb[4] = {bv.x, bv.y, bv.z, bv.w};
            #pragma unroll
            for (int i = 0; i < 4; ++i)
                #pragma unroll
                for (int j = 0; j < 4; ++j)
                    acc[i][j] += aa[i] * bb[j];
        }
        __syncthreads();
    }
    float bcol[4];
    #pragma unroll
    for (int j = 0; j < 4; ++j) bcol[j] = bias ? bias[n0 + tx*4 + j] : 0.f;
    #pragma unroll
    for (int i = 0; i < 4; ++i) {
        float4 o;
        o.x = acc[i][0] + bcol[0];
        o.y = acc[i][1] + bcol[1];
        o.z = acc[i][2] + bcol[2];
        o.w = acc[i][3] + bcol[3];
        if (act) { o.x = silu_f(o.x); o.y = silu_f(o.y); o.z = silu_f(o.z); o.w = silu_f(o.w); }
        *(float4*)&C[(size_t)(m0 + ty*4 + i) * Nc + n0 + tx*4] = o;
    }
}

// ---------------- atom-centric message gather (atomic-free) ----------------
__global__ __launch_bounds__(128) void msg_gather(
    const float* __restrict__ phi, const float* __restrict__ rbfe,
    const float* __restrict__ envb, const float* __restrict__ unitb,
    const int* __restrict__ nbrs, const float* __restrict__ rbf_w,
    const float* __restrict__ rbf_b, const float* __restrict__ v_in,
    float* __restrict__ s, float* __restrict__ v_out,
    const int* __restrict__ sorted_eid, const int* __restrict__ offsets,
    const int* __restrict__ cnt)
{
    const int n = blockIdx.x, tid = threadIdx.x;
    const size_t NF = (size_t)NP * F;      // plane stride (padded)
    float W0[N_RBF], W1[N_RBF], W2[N_RBF];
    #pragma unroll
    for (int k = 0; k < N_RBF; ++k) {
        W0[k] = rbf_w[k*3*F + tid];
        W1[k] = rbf_w[k*3*F + F + tid];
        W2[k] = rbf_w[k*3*F + 2*F + tid];
    }
    const float b0 = rbf_b[tid], b1 = rbf_b[F + tid], b2 = rbf_b[2*F + tid];
    float ds = 0.f, dvx = 0.f, dvy = 0.f, dvz = 0.f;
    const int off = offsets[n], c = cnt[n];
    for (int t = 0; t < c; ++t) {
        int e = sorted_eid[off + t];
        int j = nbrs[2*e+1];
        float ev = envb[e];
        float ux = unitb[3*e+0], uy = unitb[3*e+1], uz = unitb[3*e+2];
        float w0 = b0 * ev, w1 = b1 * ev, w2 = b2 * ev;
        #pragma unroll
        for (int k = 0; k < N_RBF; ++k) {
            float rk = rbfe[e*N_RBF + k];
            w0 += rk * W0[k]; w1 += rk * W1[k]; w2 += rk * W2[k];
        }
        const float* prow = phi + (size_t)j * 3 * F;
        float s0 = prow[tid] * w0;
        float s1 = prow[F + tid] * w1;
        float s2 = prow[2*F + tid] * w2;
        ds  += s1;
        dvx += s2*ux + s0 * v_in[(size_t)j*F + tid];
        dvy += s2*uy + s0 * v_in[NF   + (size_t)j*F + tid];
        dvz += s2*uz + s0 * v_in[2*NF + (size_t)j*F + tid];
    }
    size_t idx = (size_t)n * F + tid;
    s[idx] += ds;
    v_out[idx]        = v_in[idx]        + dvx;
    v_out[NF + idx]   = v_in[NF + idx]   + dvy;
    v_out[2*NF + idx] = v_in[2*NF + idx] + dvz;
}

// ---------------- stack = [s | ||v_v||] ----------------
__global__ __launch_bounds__(256) void stack_kernel(
    const float* __restrict__ s, const float* __restrict__ vv, float* __restrict__ stk)
{
    size_t idx = (size_t)blockIdx.x * 256 + threadIdx.x;   // < N_ATOMS*F
    const size_t NF = (size_t)NP * F;
    int n = (int)(idx >> 7), f = (int)(idx & 127);
    float x = vv[idx], y = vv[NF + idx], z2 = vv[2*NF + idx];
    float nrm = sqrtf(x*x + y*y + z2*z2 + 1e-15f);
    stk[(size_t)n*2*F + f]     = s[idx];
    stk[(size_t)n*2*F + F + f] = nrm;
}

// ---------------- final conv update ----------------
__global__ __launch_bounds__(256) void finupd_kernel(
    const float* __restrict__ uv, const float* __restrict__ vv,
    const float* __restrict__ a, float* __restrict__ s, float* __restrict__ v)
{
    size_t idx = (size_t)blockIdx.x * 256 + threadIdx.x;   // < N_ATOMS*F
    const size_t NF = (size_t)NP * F;
    int n = (int)(idx >> 7), f = (int)(idx & 127);
    float ux = uv[idx], uy = uv[NF + idx], uz = uv[2*NF + idx];
    float wx = vv[idx], wy = vv[NF + idx], wz = vv[2*NF + idx];
    float dot = ux*wx + uy*wy + uz*wz;
    const float* arow = a + (size_t)n * 3 * F;
    s[idx] += dot * arow[F + f] + arow[2*F + f];
    float avv = arow[f];
    v[idx]        += ux * avv;
    v[NF + idx]   += uy * avv;
    v[2*NF + idx] += uz * avv;
}

// ---------------- readout reduce ----------------
__global__ __launch_bounds__(256) void readout_kernel(
    const float* __restrict__ hr, const float* __restrict__ w2,
    const float* __restrict__ b2, const int* __restrict__ mol, float* __restrict__ out)
{
    int lane = threadIdx.x & 63;
    int n = blockIdx.x * 4 + (threadIdx.x >> 6);   // grid sized exactly N_ATOMS/4
    float val = hr[(size_t)n * 64 + lane] * w2[lane];
    #pragma unroll
    for (int offd = 32; offd > 0; offd >>= 1) val += __shfl_down(val, offd);
    if (lane == 0) atomicAdd(&out[mol[n]], val + b2[0]);
}

extern "C" void kernel_launch(void* const* d_in, const int* in_sizes, int n_in,
                              void* d_out, int out_size, void* d_ws, size_t ws_size,
                              hipStream_t stream)
{
    const float* xyz    = (const float*)d_in[0];
    const float* emb    = (const float*)d_in[1];
    const float* msg_w1 = (const float*)d_in[2];
    const float* msg_b1 = (const float*)d_in[3];
    const float* msg_w2 = (const float*)d_in[4];
    const float* msg_b2 = (const float*)d_in[5];
    const float* rbf_w  = (const float*)d_in[6];
    const float* rbf_b  = (const float*)d_in[7];
    const float* upd_u  = (const float*)d_in[8];
    const float* upd_v  = (const float*)d_in[9];
    const float* upd_w1 = (const float*)d_in[10];
    const float* upd_b1 = (const float*)d_in[11];
    const float* upd_w2 = (const float*)d_in[12];
    const float* upd_b2 = (const float*)d_in[13];
    const float* ro_w1  = (const float*)d_in[14];
    const float* ro_b1  = (const float*)d_in[15];
    const float* ro_w2  = (const float*)d_in[16];
    const float* ro_b2  = (const float*)d_in[17];
    const int*   z      = (const int*)d_in[18];
    const int*   nbrs   = (const int*)d_in[19];
    const int*   molidx = (const int*)d_in[20];
    float* out = (float*)d_out;

    float* ws = (float*)d_ws;
    size_t off = 0;
    auto alloc = [&](size_t n) { float* p = ws + off; off += n; return p; };
    const size_t NF = (size_t)NP * F;      // padded plane stride
    float* s_buf   = alloc(NF);            // s (updated in-place)
    float* v1_buf  = alloc(3 * NF);        // v ping
    float* v2_buf  = alloc(3 * NF);        // v pong
    float* uv_buf  = alloc(3 * NF);        // u_v planes
    float* vv_buf  = alloc(3 * NF);        // v_v planes
    float* phi_buf = alloc(3 * NF);        // phi (NPx384), reused as 'a'
    float* h_buf   = alloc(NF);            // MLP hidden / readout hidden
    float* stk_buf = alloc(2 * NF);        // [s | norm]
    float* rbfe    = alloc((size_t)N_EDGES * N_RBF);
    float* envb    = alloc(N_EDGES);
    float* unitb   = alloc((size_t)N_EDGES * 3);
    int* cnt        = (int*)alloc(N_ATOMS);
    int* cursor     = (int*)alloc(N_ATOMS);
    int* offsets    = (int*)alloc(N_ATOMS);
    int* sorted_eid = (int*)alloc(N_EDGES);

    hipMemsetAsync(out, 0, sizeof(float) * N_MOLS, stream);
    hipMemsetAsync(v1_buf, 0, sizeof(float) * 3 * NF, stream);
    hipMemsetAsync(cnt, 0, sizeof(int) * 2 * N_ATOMS, stream);   // cnt + cursor adjacent

    geom_kernel<<<dim3((N_EDGES + 255) / 256), dim3(256), 0, stream>>>(
        xyz, nbrs, rbfe, envb, unitb, cnt);
    scan_kernel<<<dim3(1), dim3(1024), 0, stream>>>(cnt, offsets);
    scatter_kernel<<<dim3((N_EDGES + 255) / 256), dim3(256), 0, stream>>>(
        nbrs, envb, offsets, cursor, sorted_eid);
    embed_kernel<<<dim3(N_ATOMS * F / 256), dim3(256), 0, stream>>>(emb, z, s_buf);

    float* vin = v1_buf;
    float* vout = v2_buf;
    for (int i = 0; i < 3; ++i) {
        // phi = silu(s@W1+b1)@W2+b2
        gemm_big<64><<<dim3(1, NP/64), dim3(256), 0, stream>>>(
            s_buf, msg_w1 + (size_t)i*F*F, msg_b1 + (size_t)i*F, h_buf, F, F, 1);
        gemm_big<128><<<dim3(3, NP/128), dim3(256), 0, stream>>>(
            h_buf, msg_w2 + (size_t)i*F*3*F, msg_b2 + (size_t)i*3*F, phi_buf, F, 3*F, 0);
        // atomic-free message gather: s += ds in place; vout = vin + dv
        msg_gather<<<dim3(N_ATOMS), dim3(128), 0, stream>>>(
            phi_buf, rbfe, envb, unitb, nbrs,
            rbf_w + (size_t)i*N_RBF*3*F, rbf_b + (size_t)i*3*F,
            vin, s_buf, vout, sorted_eid, offsets, cnt);
        // u_v / v_v: batched over 3 dims as M=3*NP GEMM
        gemm_big<128><<<dim3(1, 3*NP/128), dim3(256), 0, stream>>>(
            vout, upd_u + (size_t)i*F*F, nullptr, uv_buf, F, F, 0);
        gemm_big<128><<<dim3(1, 3*NP/128), dim3(256), 0, stream>>>(
            vout, upd_v + (size_t)i*F*F, nullptr, vv_buf, F, F, 0);
        stack_kernel<<<dim3(N_ATOMS * F / 256), dim3(256), 0, stream>>>(s_buf, vv_buf, stk_buf);
        // a = silu(stack@W1+b1)@W2+b2   (a lands in phi_buf — phi no longer needed)
        gemm_big<64><<<dim3(1, NP/64), dim3(256), 0, stream>>>(
            stk_buf, upd_w1 + (size_t)i*2*F*F, upd_b1 + (size_t)i*F, h_buf, 2*F, F, 1);
        gemm_big<128><<<dim3(3, NP/128), dim3(256), 0, stream>>>(
            h_buf, upd_w2 + (size_t)i*F*3*F, upd_b2 + (size_t)i*3*F, phi_buf, F, 3*F, 0);
        finupd_kernel<<<dim3(N_ATOMS * F / 256), dim3(256), 0, stream>>>(
            uv_buf, vv_buf, phi_buf, s_buf, vout);
        float* tmp = vin; vin = vout; vout = tmp;
    }

    // readout
    gemm_bias_act<<<dim3(1, NP/64), dim3(256), 0, stream>>>(
        s_buf, ro_w1, ro_b1, h_buf, NP, F, 64, 1);
    readout_kernel<<<dim3(N_ATOMS/4), dim3(256), 0, stream>>>(h_buf, ro_w2, ro_b2, molidx, out);
}

// Round 5
// 565.849 us; speedup vs baseline: 1.2192x; 1.2192x over previous
//
#include <hip/hip_runtime.h>

static constexpr int F = 128;
static constexpr int N_RBF = 20;
static constexpr int N_ATOMS = 8000;
static constexpr int NP = 8064;          // padded to 128 (pad rows hold harness poison = tiny normal floats, benign)
static constexpr int N_EDGES = 160000;
static constexpr int N_MOLS = 100;
static constexpr float CUTOFF = 5.0f;
#define PIF 3.14159265358979323846f

typedef __attribute__((ext_vector_type(8))) short bf16x8;
typedef __attribute__((ext_vector_type(4))) float f32x4;
typedef unsigned short ushort_t;
typedef unsigned int uint_t;

__device__ __forceinline__ float silu_f(float x) { return x / (1.f + __expf(-x)); }

__device__ __forceinline__ ushort_t f2bf(float x) {   // round-to-nearest-even
    union { float f; uint_t u; } v; v.f = x;
    uint_t r = v.u + 0x7fffu + ((v.u >> 16) & 1u);
    return (ushort_t)(r >> 16);
}
__device__ __forceinline__ float bf2f(ushort_t h) {
    union { uint_t u; float f; } v; v.u = ((uint_t)h) << 16; return v.f;
}

// ---------------- edge geometry + live-edge histogram ----------------
__global__ __launch_bounds__(256) void geom_kernel(
    const float* __restrict__ xyz, const int* __restrict__ nbrs,
    float* __restrict__ rbfe, float* __restrict__ envb, float* __restrict__ unitb,
    int* __restrict__ cnt)
{
    int e = blockIdx.x * 256 + threadIdx.x;
    if (e >= N_EDGES) return;
    int i0 = nbrs[2*e+0], i1 = nbrs[2*e+1];
    float dx = xyz[3*i1+0] - xyz[3*i0+0];
    float dy = xyz[3*i1+1] - xyz[3*i0+1];
    float dz = xyz[3*i1+2] - xyz[3*i0+2];
    float d  = sqrtf(dx*dx + dy*dy + dz*dz);
    float inv = 1.f / d;
    unitb[3*e+0] = dx*inv; unitb[3*e+1] = dy*inv; unitb[3*e+2] = dz*inv;
    float ev = (d <= CUTOFF) ? 0.5f*(cosf(PIF*d/CUTOFF) + 1.f) : 0.f;
    envb[e] = ev;
    float base = PIF*d/CUTOFF;
    float sc = inv * ev;   // fold env into rbf (w_s = (rbf*env)@W + b*env)
    #pragma unroll
    for (int k = 0; k < N_RBF; ++k)
        rbfe[e*N_RBF + k] = sinf((float)(k+1)*base) * sc;
    if (ev > 0.f) atomicAdd(&cnt[i0], 1);
}

// ---------------- exclusive scan of 8000 counters (single block) ----------------
__global__ __launch_bounds__(1024) void scan_kernel(
    const int* __restrict__ cnt, int* __restrict__ offsets)
{
    __shared__ int sums[1024];
    int tid = threadIdx.x;
    int base = tid * 8;
    int local[8]; int s = 0;
    #pragma unroll
    for (int i = 0; i < 8; ++i) {
        int idx = base + i;
        local[i] = (idx < N_ATOMS) ? cnt[idx] : 0;
        s += local[i];
    }
    sums[tid] = s;
    __syncthreads();
    for (int d = 1; d < 1024; d <<= 1) {
        int v = (tid >= d) ? sums[tid - d] : 0;
        __syncthreads();
        sums[tid] += v;
        __syncthreads();
    }
    int ex = (tid == 0) ? 0 : sums[tid - 1];
    #pragma unroll
    for (int i = 0; i < 8; ++i) {
        int idx = base + i;
        if (idx < N_ATOMS) { offsets[idx] = ex; ex += local[i]; }
    }
}

// ---------------- scatter live edge ids into per-atom segments ----------------
__global__ __launch_bounds__(256) void scatter_kernel(
    const int* __restrict__ nbrs, const float* __restrict__ envb,
    const int* __restrict__ offsets, int* __restrict__ cursor,
    int* __restrict__ sorted_eid)
{
    int e = blockIdx.x * 256 + threadIdx.x;
    if (e >= N_EDGES) return;
    if (envb[e] <= 0.f) return;
    int tgt = nbrs[2*e+0];
    int pos = offsets[tgt] + atomicAdd(&cursor[tgt], 1);
    sorted_eid[pos] = e;
}

// ---------------- s = emb_table[z] ----------------
__global__ __launch_bounds__(256) void embed_kernel(
    const float* __restrict__ emb, const int* __restrict__ z, float* __restrict__ s)
{
    int idx = blockIdx.x * 256 + threadIdx.x;   // grid sized exactly N_ATOMS*F
    int n = idx >> 7, f = idx & 127;
    s[idx] = emb[z[n]*F + f];
}

// ---------------- weight prep: transpose + f32 -> (bf16 hi, bf16 lo) ----------------
// dst layout (bf16, [n][k] row-major K-contig), same offsets for hi and lo buffers:
//   W1t  3x(128n x 128k) @ 0        src msg_w1 (128k x 128n)
//   W2t  3x(384n x 128k) @ 49152    src msg_w2
//   UVt  3x(256n x 128k) @ 196608   src upd_u (n 0..127) | upd_v (n 128..255)
//   U1t  3x(128n x 256k) @ 294912   src upd_w1 (256k x 128n)
//   U2t  3x(384n x 128k) @ 393216   src upd_w2
static constexpr int WPREP_TOTAL = 540672;
__global__ __launch_bounds__(256) void wprep_kernel(
    const float* __restrict__ msg_w1, const float* __restrict__ msg_w2,
    const float* __restrict__ upd_u,  const float* __restrict__ upd_v,
    const float* __restrict__ upd_w1, const float* __restrict__ upd_w2,
    ushort_t* __restrict__ dhi, ushort_t* __restrict__ dlo)
{
    int idx = blockIdx.x * 256 + threadIdx.x;
    if (idx >= WPREP_TOTAL) return;
    const float* src; int K, N, rem;
    if (idx < 49152)       { int l = idx;          int c = l / 16384; rem = l % 16384; K = 128; N = 128; src = msg_w1 + c * 16384; }
    else if (idx < 196608) { int l = idx - 49152;  int c = l / 49152; rem = l % 49152; K = 128; N = 384; src = msg_w2 + c * 49152; }
    else if (idx < 294912) { int l = idx - 196608; int c = l / 32768; rem = l % 32768; K = 128; N = 128;
                             if (rem < 16384) src = upd_u + c * 16384;
                             else { src = upd_v + c * 16384; rem -= 16384; } }
    else if (idx < 393216) { int l = idx - 294912; int c = l / 32768; rem = l % 32768; K = 256; N = 128; src = upd_w1 + c * 32768; }
    else                   { int l = idx - 393216; int c = l / 49152; rem = l % 49152; K = 128; N = 384; src = upd_w2 + c * 49152; }
    int n = rem / K, k = rem % K;
    float val = src[k * N + n];
    ushort_t h = f2bf(val);
    dhi[idx] = h;
    dlo[idx] = f2bf(val - bf2f(h));
}

// ---------------- MFMA bf16x3 GEMM: C = act(A@B + bias), split-column epilogue ----------------
// f32 accuracy via hi/lo bf16 decomposition: A@B ~= Ah@Bh + Ah@Bl + Al@Bh (drop lo*lo, ~2^-18 rel).
// A: MxK f32 row-major (split to hi/lo during staging). Bhi/Blo: Nc x K bf16 (K-contig).
// Tile 128x128, 256 threads = 4 waves (2x2 of 64x64), mfma_f32_16x16x32_bf16.
// M%128==0, Nc%128==0, K%32==0. Columns >= split go to C1 (for fused u_v|v_v).
__global__ __launch_bounds__(256) void gemm_mfma3(
    const float* __restrict__ A,
    const ushort_t* __restrict__ Bhi, const ushort_t* __restrict__ Blo,
    const float* __restrict__ bias, float* __restrict__ C0, float* __restrict__ C1,
    int K, int split, int ld0, int ld1, int act)
{
    __shared__ __align__(16) ushort_t Ah[128 * 40];   // [m][k], stride 40 (32 data + 8 pad)
    __shared__ __align__(16) ushort_t Al[128 * 40];
    __shared__ __align__(16) ushort_t Bh[128 * 40];   // [n][k]
    __shared__ __align__(16) ushort_t Bl[128 * 40];
    const int tid = threadIdx.x;
    const int wave = tid >> 6, lane = tid & 63;
    const int wm = (wave >> 1) * 64, wn = (wave & 1) * 64;
    const int m0 = blockIdx.y * 128, n0 = blockIdx.x * 128;
    const int row_l = lane & 15, quad = lane >> 4;
    const int lr = tid >> 1;            // staging row 0..127
    const int seg = (tid & 1) * 16;     // staging k-segment

    f32x4 acc[4][4];
    #pragma unroll
    for (int i = 0; i < 4; ++i)
        #pragma unroll
        for (int j = 0; j < 4; ++j)
            #pragma unroll
            for (int r = 0; r < 4; ++r) acc[i][j][r] = 0.f;

    for (int k0 = 0; k0 < K; k0 += 32) {
        // stage A: 128 x 32 f32 -> (hi, lo) bf16 (16 elems/thread)
        {
            const float* ap = &A[(size_t)(m0 + lr) * K + k0 + seg];
            union { ushort_t u[16]; uint4 q[2]; } ph, pl;
            #pragma unroll
            for (int qq = 0; qq < 4; ++qq) {
                float4 v = *(const float4*)(ap + qq * 4);
                float e[4] = {v.x, v.y, v.z, v.w};
                #pragma unroll
                for (int t = 0; t < 4; ++t) {
                    ushort_t h = f2bf(e[t]);
                    ph.u[qq*4+t] = h;
                    pl.u[qq*4+t] = f2bf(e[t] - bf2f(h));
                }
            }
            *(uint4*)&Ah[lr * 40 + seg]     = ph.q[0];
            *(uint4*)&Ah[lr * 40 + seg + 8] = ph.q[1];
            *(uint4*)&Al[lr * 40 + seg]     = pl.q[0];
            *(uint4*)&Al[lr * 40 + seg + 8] = pl.q[1];
        }
        // stage B: 128 x 32 bf16 hi + lo (pre-split in wprep)
        {
            const ushort_t* bph = &Bhi[(size_t)(n0 + lr) * K + k0 + seg];
            const ushort_t* bpl = &Blo[(size_t)(n0 + lr) * K + k0 + seg];
            *(uint4*)&Bh[lr * 40 + seg]     = *(const uint4*)bph;
            *(uint4*)&Bh[lr * 40 + seg + 8] = *(const uint4*)(bph + 8);
            *(uint4*)&Bl[lr * 40 + seg]     = *(const uint4*)bpl;
            *(uint4*)&Bl[lr * 40 + seg + 8] = *(const uint4*)(bpl + 8);
        }
        __syncthreads();
        bf16x8 ahf[4], alf[4], bhf[4], blf[4];
        #pragma unroll
        for (int i = 0; i < 4; ++i) {
            int ar = (wm + i*16 + row_l) * 40 + quad * 8;
            int br = (wn + i*16 + row_l) * 40 + quad * 8;
            ahf[i] = *(const bf16x8*)&Ah[ar];
            alf[i] = *(const bf16x8*)&Al[ar];
            bhf[i] = *(const bf16x8*)&Bh[br];
            blf[i] = *(const bf16x8*)&Bl[br];
        }
        #pragma unroll
        for (int i = 0; i < 4; ++i)
            #pragma unroll
            for (int j = 0; j < 4; ++j) {
                acc[i][j] = __builtin_amdgcn_mfma_f32_16x16x32_bf16(ahf[i], bhf[j], acc[i][j], 0, 0, 0);
                acc[i][j] = __builtin_amdgcn_mfma_f32_16x16x32_bf16(ahf[i], blf[j], acc[i][j], 0, 0, 0);
                acc[i][j] = __builtin_amdgcn_mfma_f32_16x16x32_bf16(alf[i], bhf[j], acc[i][j], 0, 0, 0);
            }
        __syncthreads();
    }

    // epilogue: D[row][col]: col = lane&15 (+tile), row = quad*4 + r (+tile)
    #pragma unroll
    for (int j = 0; j < 4; ++j) {
        int col = n0 + wn + j * 16 + row_l;
        float bval = bias ? bias[col] : 0.f;
        float* Cp; int ccol, ld;
        if (col < split) { Cp = C0; ccol = col; ld = ld0; }
        else             { Cp = C1; ccol = col - split; ld = ld1; }
        #pragma unroll
        for (int i = 0; i < 4; ++i) {
            #pragma unroll
            for (int r = 0; r < 4; ++r) {
                int row = m0 + wm + i * 16 + quad * 4 + r;
                float v = acc[i][j][r] + bval;
                if (act) v = silu_f(v);
                Cp[(size_t)row * ld + ccol] = v;
            }
        }
    }
}

// ---------------- small f32 GEMM (readout only): 64x64 tile, 4x4 ----------------
__global__ __launch_bounds__(256) void gemm_bias_act(
    const float* __restrict__ A, const float* __restrict__ B,
    const float* __restrict__ bias, float* __restrict__ C,
    int M, int K, int Nc, int act)
{
    __shared__ float As[16][68];
    __shared__ float Bs[16][64];
    const int tid = threadIdx.x;
    const int tx = tid & 15, ty = tid >> 4;
    const int m0 = blockIdx.y * 64, n0 = blockIdx.x * 64;
    float acc[4][4] = {};
    const int ka = tid & 15;
    const int ma = tid >> 4;
    const int kb = tid >> 4;
    const int cb = (tid & 15) * 4;
    for (int k0 = 0; k0 < K; k0 += 16) {
        #pragma unroll
        for (int r = 0; r < 4; ++r)
            As[ka][ma + 16*r] = A[(size_t)(m0 + ma + 16*r) * K + k0 + ka];
        *(float4*)&Bs[kb][cb] = *(const float4*)&B[(size_t)(k0 + kb) * Nc + n0 + cb];
        __syncthreads();
        #pragma unroll
        for (int kk = 0; kk < 16; ++kk) {
            float4 av = *(const float4*)&As[kk][ty*4];
            float4 bv = *(const float4*)&Bs[kk][tx*4];
            float aa[4] = {av.x, av.y, av.z, av.w};
            float bb[4] = {bv.x, bv.y, bv.z, bv.w};
            #pragma unroll
            for (int i = 0; i < 4; ++i)
                #pragma unroll
                for (int j = 0; j < 4; ++j)
                    acc[i][j] += aa[i] * bb[j];
        }
        __syncthreads();
    }
    float bcol[4];
    #pragma unroll
    for (int j = 0; j < 4; ++j) bcol[j] = bias ? bias[n0 + tx*4 + j] : 0.f;
    #pragma unroll
    for (int i = 0; i < 4; ++i) {
        float4 o;
        o.x = acc[i][0] + bcol[0];
        o.y = acc[i][1] + bcol[1];
        o.z = acc[i][2] + bcol[2];
        o.w = acc[i][3] + bcol[3];
        if (act) { o.x = silu_f(o.x); o.y = silu_f(o.y); o.z = silu_f(o.z); o.w = silu_f(o.w); }
        *(float4*)&C[(size_t)(m0 + ty*4 + i) * Nc + n0 + tx*4] = o;
    }
}

// ---------------- atom-centric message gather (atomic-free) ----------------
__global__ __launch_bounds__(128) void msg_gather(
    const float* __restrict__ phi, const float* __restrict__ rbfe,
    const float* __restrict__ envb, const float* __restrict__ unitb,
    const int* __restrict__ nbrs, const float* __restrict__ rbf_w,
    const float* __restrict__ rbf_b, const float* __restrict__ v_in,
    float* __restrict__ s, float* __restrict__ v_out,
    const int* __restrict__ sorted_eid, const int* __restrict__ offsets,
    const int* __restrict__ cnt)
{
    const int n = blockIdx.x, tid = threadIdx.x;
    const size_t NF = (size_t)NP * F;      // plane stride (padded)
    float W0[N_RBF], W1[N_RBF], W2[N_RBF];
    #pragma unroll
    for (int k = 0; k < N_RBF; ++k) {
        W0[k] = rbf_w[k*3*F + tid];
        W1[k] = rbf_w[k*3*F + F + tid];
        W2[k] = rbf_w[k*3*F + 2*F + tid];
    }
    const float b0 = rbf_b[tid], b1 = rbf_b[F + tid], b2 = rbf_b[2*F + tid];
    float ds = 0.f, dvx = 0.f, dvy = 0.f, dvz = 0.f;
    const int off = offsets[n], c = cnt[n];
    for (int t = 0; t < c; ++t) {
        int e = sorted_eid[off + t];
        int j = nbrs[2*e+1];
        float ev = envb[e];
        float ux = unitb[3*e+0], uy = unitb[3*e+1], uz = unitb[3*e+2];
        float w0 = b0 * ev, w1 = b1 * ev, w2 = b2 * ev;
        #pragma unroll
        for (int k = 0; k < N_RBF; ++k) {
            float rk = rbfe[e*N_RBF + k];
            w0 += rk * W0[k]; w1 += rk * W1[k]; w2 += rk * W2[k];
        }
        const float* prow = phi + (size_t)j * 3 * F;
        float s0 = prow[tid] * w0;
        float s1 = prow[F + tid] * w1;
        float s2 = prow[2*F + tid] * w2;
        ds  += s1;
        dvx += s2*ux + s0 * v_in[(size_t)j*F + tid];
        dvy += s2*uy + s0 * v_in[NF   + (size_t)j*F + tid];
        dvz += s2*uz + s0 * v_in[2*NF + (size_t)j*F + tid];
    }
    size_t idx = (size_t)n * F + tid;
    s[idx] += ds;
    v_out[idx]        = v_in[idx]        + dvx;
    v_out[NF + idx]   = v_in[NF + idx]   + dvy;
    v_out[2*NF + idx] = v_in[2*NF + idx] + dvz;
}

// ---------------- stack = [s | ||v_v||] ----------------
__global__ __launch_bounds__(256) void stack_kernel(
    const float* __restrict__ s, const float* __restrict__ vv, float* __restrict__ stk)
{
    size_t idx = (size_t)blockIdx.x * 256 + threadIdx.x;   // < N_ATOMS*F
    const size_t NF = (size_t)NP * F;
    int n = (int)(idx >> 7), f = (int)(idx & 127);
    float x = vv[idx], y = vv[NF + idx], z2 = vv[2*NF + idx];
    float nrm = sqrtf(x*x + y*y + z2*z2 + 1e-15f);
    stk[(size_t)n*2*F + f]     = s[idx];
    stk[(size_t)n*2*F + F + f] = nrm;
}

// ---------------- final conv update ----------------
__global__ __launch_bounds__(256) void finupd_kernel(
    const float* __restrict__ uv, const float* __restrict__ vv,
    const float* __restrict__ a, float* __restrict__ s, float* __restrict__ v)
{
    size_t idx = (size_t)blockIdx.x * 256 + threadIdx.x;   // < N_ATOMS*F
    const size_t NF = (size_t)NP * F;
    int n = (int)(idx >> 7), f = (int)(idx & 127);
    float ux = uv[idx], uy = uv[NF + idx], uz = uv[2*NF + idx];
    float wx = vv[idx], wy = vv[NF + idx], wz = vv[2*NF + idx];
    float dot = ux*wx + uy*wy + uz*wz;
    const float* arow = a + (size_t)n * 3 * F;
    s[idx] += dot * arow[F + f] + arow[2*F + f];
    float avv = arow[f];
    v[idx]        += ux * avv;
    v[NF + idx]   += uy * avv;
    v[2*NF + idx] += uz * avv;
}

// ---------------- readout reduce ----------------
__global__ __launch_bounds__(256) void readout_kernel(
    const float* __restrict__ hr, const float* __restrict__ w2,
    const float* __restrict__ b2, const int* __restrict__ mol, float* __restrict__ out)
{
    int lane = threadIdx.x & 63;
    int n = blockIdx.x * 4 + (threadIdx.x >> 6);   // grid sized exactly N_ATOMS/4
    float val = hr[(size_t)n * 64 + lane] * w2[lane];
    #pragma unroll
    for (int offd = 32; offd > 0; offd >>= 1) val += __shfl_down(val, offd);
    if (lane == 0) atomicAdd(&out[mol[n]], val + b2[0]);
}

extern "C" void kernel_launch(void* const* d_in, const int* in_sizes, int n_in,
                              void* d_out, int out_size, void* d_ws, size_t ws_size,
                              hipStream_t stream)
{
    const float* xyz    = (const float*)d_in[0];
    const float* emb    = (const float*)d_in[1];
    const float* msg_w1 = (const float*)d_in[2];
    const float* msg_b1 = (const float*)d_in[3];
    const float* msg_w2 = (const float*)d_in[4];
    const float* msg_b2 = (const float*)d_in[5];
    const float* rbf_w  = (const float*)d_in[6];
    const float* rbf_b  = (const float*)d_in[7];
    const float* upd_u  = (const float*)d_in[8];
    const float* upd_v  = (const float*)d_in[9];
    const float* upd_w1 = (const float*)d_in[10];
    const float* upd_b1 = (const float*)d_in[11];
    const float* upd_w2 = (const float*)d_in[12];
    const float* upd_b2 = (const float*)d_in[13];
    const float* ro_w1  = (const float*)d_in[14];
    const float* ro_b1  = (const float*)d_in[15];
    const float* ro_w2  = (const float*)d_in[16];
    const float* ro_b2  = (const float*)d_in[17];
    const int*   z      = (const int*)d_in[18];
    const int*   nbrs   = (const int*)d_in[19];
    const int*   molidx = (const int*)d_in[20];
    float* out = (float*)d_out;

    float* ws = (float*)d_ws;
    size_t off = 0;
    auto alloc = [&](size_t n) { float* p = ws + off; off += n; return p; };
    const size_t NF = (size_t)NP * F;      // padded plane stride
    float* s_buf   = alloc(NF);
    float* v1_buf  = alloc(3 * NF);
    float* v2_buf  = alloc(3 * NF);
    float* uv_buf  = alloc(3 * NF);
    float* vv_buf  = alloc(3 * NF);
    float* phi_buf = alloc(3 * NF);
    float* h_buf   = alloc(NF);
    float* stk_buf = alloc(2 * NF);
    float* rbfe    = alloc((size_t)N_EDGES * N_RBF);
    float* envb    = alloc(N_EDGES);
    float* unitb   = alloc((size_t)N_EDGES * 3);
    ushort_t* wbf_hi = (ushort_t*)alloc(WPREP_TOTAL / 2 + 64);   // bf16 weight hi
    ushort_t* wbf_lo = (ushort_t*)alloc(WPREP_TOTAL / 2 + 64);   // bf16 weight lo
    int* cnt        = (int*)alloc(N_ATOMS);
    int* cursor     = (int*)alloc(N_ATOMS);
    int* offsets    = (int*)alloc(N_ATOMS);
    int* sorted_eid = (int*)alloc(N_EDGES);

    // bf16 weight sub-offsets (elements, see wprep_kernel)
    const size_t oW1 = 0, oW2 = 49152, oUV = 196608, oU1 = 294912, oU2 = 393216;

    hipMemsetAsync(out, 0, sizeof(float) * N_MOLS, stream);
    hipMemsetAsync(v1_buf, 0, sizeof(float) * 3 * NF, stream);
    hipMemsetAsync(cnt, 0, sizeof(int) * 2 * N_ATOMS, stream);   // cnt + cursor adjacent

    geom_kernel<<<dim3((N_EDGES + 255) / 256), dim3(256), 0, stream>>>(
        xyz, nbrs, rbfe, envb, unitb, cnt);
    scan_kernel<<<dim3(1), dim3(1024), 0, stream>>>(cnt, offsets);
    scatter_kernel<<<dim3((N_EDGES + 255) / 256), dim3(256), 0, stream>>>(
        nbrs, envb, offsets, cursor, sorted_eid);
    embed_kernel<<<dim3(N_ATOMS * F / 256), dim3(256), 0, stream>>>(emb, z, s_buf);
    wprep_kernel<<<dim3((WPREP_TOTAL + 255) / 256), dim3(256), 0, stream>>>(
        msg_w1, msg_w2, upd_u, upd_v, upd_w1, upd_w2, wbf_hi, wbf_lo);

    float* vin = v1_buf;
    float* vout = v2_buf;
    for (int i = 0; i < 3; ++i) {
        // phi = silu(s@W1+b1)@W2+b2
        gemm_mfma3<<<dim3(1, NP/128), dim3(256), 0, stream>>>(
            s_buf, wbf_hi + oW1 + (size_t)i*16384, wbf_lo + oW1 + (size_t)i*16384,
            msg_b1 + (size_t)i*F, h_buf, h_buf, F, F, F, F, 1);
        gemm_mfma3<<<dim3(3, NP/128), dim3(256), 0, stream>>>(
            h_buf, wbf_hi + oW2 + (size_t)i*49152, wbf_lo + oW2 + (size_t)i*49152,
            msg_b2 + (size_t)i*3*F, phi_buf, phi_buf, F, 3*F, 3*F, 3*F, 0);
        // atomic-free message gather: s += ds in place; vout = vin + dv
        msg_gather<<<dim3(N_ATOMS), dim3(128), 0, stream>>>(
            phi_buf, rbfe, envb, unitb, nbrs,
            rbf_w + (size_t)i*N_RBF*3*F, rbf_b + (size_t)i*3*F,
            vin, s_buf, vout, sorted_eid, offsets, cnt);
        // fused u_v|v_v: one GEMM, A read once, split-column epilogue
        gemm_mfma3<<<dim3(2, 3*NP/128), dim3(256), 0, stream>>>(
            vout, wbf_hi + oUV + (size_t)i*32768, wbf_lo + oUV + (size_t)i*32768,
            nullptr, uv_buf, vv_buf, F, F, F, F, 0);
        stack_kernel<<<dim3(N_ATOMS * F / 256), dim3(256), 0, stream>>>(s_buf, vv_buf, stk_buf);
        // a = silu(stack@W1+b1)@W2+b2   (a lands in phi_buf)
        gemm_mfma3<<<dim3(1, NP/128), dim3(256), 0, stream>>>(
            stk_buf, wbf_hi + oU1 + (size_t)i*32768, wbf_lo + oU1 + (size_t)i*32768,
            upd_b1 + (size_t)i*F, h_buf, h_buf, 2*F, F, F, F, 1);
        gemm_mfma3<<<dim3(3, NP/128), dim3(256), 0, stream>>>(
            h_buf, wbf_hi + oU2 + (size_t)i*49152, wbf_lo + oU2 + (size_t)i*49152,
            upd_b2 + (size_t)i*3*F, phi_buf, phi_buf, F, 3*F, 3*F, 3*F, 0);
        finupd_kernel<<<dim3(N_ATOMS * F / 256), dim3(256), 0, stream>>>(
            uv_buf, vv_buf, phi_buf, s_buf, vout);
        float* tmp = vin; vin = vout; vout = tmp;
    }

    // readout (tiny, exact f32)
    gemm_bias_act<<<dim3(1, NP/64), dim3(256), 0, stream>>>(
        s_buf, ro_w1, ro_b1, h_buf, NP, F, 64, 1);
    readout_kernel<<<dim3(N_ATOMS/4), dim3(256), 0, stream>>>(h_buf, ro_w2, ro_b2, molidx, out);
}

// Round 6
// 497.510 us; speedup vs baseline: 1.3866x; 1.1374x over previous
//
#include <hip/hip_runtime.h>

static constexpr int F = 128;
static constexpr int N_RBF = 20;
static constexpr int N_ATOMS = 8000;
static constexpr int NP = 8064;          // padded to 128 (pad rows hold harness poison = tiny normal floats, benign)
static constexpr int N_EDGES = 160000;
static constexpr int N_MOLS = 100;
static constexpr float CUTOFF = 5.0f;
static constexpr size_t NFC = (size_t)NP * F;   // padded plane stride
#define PIF 3.14159265358979323846f

typedef __attribute__((ext_vector_type(8))) short bf16x8;
typedef __attribute__((ext_vector_type(4))) float f32x4;
typedef unsigned short ushort_t;
typedef unsigned int uint_t;

__device__ __forceinline__ float silu_f(float x) { return x / (1.f + __expf(-x)); }

__device__ __forceinline__ ushort_t f2bf(float x) {   // round-to-nearest-even
    union { float f; uint_t u; } v; v.f = x;
    uint_t r = v.u + 0x7fffu + ((v.u >> 16) & 1u);
    return (ushort_t)(r >> 16);
}
__device__ __forceinline__ float bf2f(ushort_t h) {
    union { uint_t u; float f; } v; v.u = ((uint_t)h) << 16; return v.f;
}

// ---------------- edge geometry + live-edge histogram ----------------
__global__ __launch_bounds__(256) void geom_kernel(
    const float* __restrict__ xyz, const int* __restrict__ nbrs,
    float* __restrict__ rbfe, float* __restrict__ envb, float* __restrict__ unitb,
    int* __restrict__ cnt)
{
    int e = blockIdx.x * 256 + threadIdx.x;
    if (e >= N_EDGES) return;
    int i0 = nbrs[2*e+0], i1 = nbrs[2*e+1];
    float dx = xyz[3*i1+0] - xyz[3*i0+0];
    float dy = xyz[3*i1+1] - xyz[3*i0+1];
    float dz = xyz[3*i1+2] - xyz[3*i0+2];
    float d  = sqrtf(dx*dx + dy*dy + dz*dz);
    float inv = 1.f / d;
    unitb[3*e+0] = dx*inv; unitb[3*e+1] = dy*inv; unitb[3*e+2] = dz*inv;
    float ev = (d <= CUTOFF) ? 0.5f*(cosf(PIF*d/CUTOFF) + 1.f) : 0.f;
    envb[e] = ev;
    float base = PIF*d/CUTOFF;
    float sc = inv * ev;   // fold env into rbf (w_s = (rbf*env)@W + b*env)
    #pragma unroll
    for (int k = 0; k < N_RBF; ++k)
        rbfe[e*N_RBF + k] = sinf((float)(k+1)*base) * sc;
    if (ev > 0.f) atomicAdd(&cnt[i0], 1);
}

// ---------------- exclusive scan of 8000 counters (single block) ----------------
__global__ __launch_bounds__(1024) void scan_kernel(
    const int* __restrict__ cnt, int* __restrict__ offsets)
{
    __shared__ int sums[1024];
    int tid = threadIdx.x;
    int base = tid * 8;
    int local[8]; int s = 0;
    #pragma unroll
    for (int i = 0; i < 8; ++i) {
        int idx = base + i;
        local[i] = (idx < N_ATOMS) ? cnt[idx] : 0;
        s += local[i];
    }
    sums[tid] = s;
    __syncthreads();
    for (int d = 1; d < 1024; d <<= 1) {
        int v = (tid >= d) ? sums[tid - d] : 0;
        __syncthreads();
        sums[tid] += v;
        __syncthreads();
    }
    int ex = (tid == 0) ? 0 : sums[tid - 1];
    #pragma unroll
    for (int i = 0; i < 8; ++i) {
        int idx = base + i;
        if (idx < N_ATOMS) { offsets[idx] = ex; ex += local[i]; }
    }
}

// ---------------- scatter live edge ids into per-atom segments ----------------
__global__ __launch_bounds__(256) void scatter_kernel(
    const int* __restrict__ nbrs, const float* __restrict__ envb,
    const int* __restrict__ offsets, int* __restrict__ cursor,
    int* __restrict__ sorted_eid)
{
    int e = blockIdx.x * 256 + threadIdx.x;
    if (e >= N_EDGES) return;
    if (envb[e] <= 0.f) return;
    int tgt = nbrs[2*e+0];
    int pos = offsets[tgt] + atomicAdd(&cursor[tgt], 1);
    sorted_eid[pos] = e;
}

// ---------------- s = emb_table[z] ----------------
__global__ __launch_bounds__(256) void embed_kernel(
    const float* __restrict__ emb, const int* __restrict__ z, float* __restrict__ s)
{
    int idx = blockIdx.x * 256 + threadIdx.x;   // grid sized exactly N_ATOMS*F
    int n = idx >> 7, f = idx & 127;
    s[idx] = emb[z[n]*F + f];
}

// ---------------- weight prep: transpose + f32 -> (bf16 hi, bf16 lo) ----------------
// dst layout (bf16, [n][k] row-major K-contig), same offsets for hi and lo buffers:
//   W1t  3x(128n x 128k) @ 0        src msg_w1 (128k x 128n)
//   W2t  3x(384n x 128k) @ 49152    src msg_w2
//   UVt  3x(256n x 128k) @ 196608   src upd_u (n 0..127) | upd_v (n 128..255)
//   U1t  3x(128n x 256k) @ 294912   src upd_w1 (256k x 128n)
//   U2t  3x(384n x 128k) @ 393216   src upd_w2
static constexpr int WPREP_TOTAL = 540672;
__global__ __launch_bounds__(256) void wprep_kernel(
    const float* __restrict__ msg_w1, const float* __restrict__ msg_w2,
    const float* __restrict__ upd_u,  const float* __restrict__ upd_v,
    const float* __restrict__ upd_w1, const float* __restrict__ upd_w2,
    ushort_t* __restrict__ dhi, ushort_t* __restrict__ dlo)
{
    int idx = blockIdx.x * 256 + threadIdx.x;
    if (idx >= WPREP_TOTAL) return;
    const float* src; int K, N, rem;
    if (idx < 49152)       { int l = idx;          int c = l / 16384; rem = l % 16384; K = 128; N = 128; src = msg_w1 + c * 16384; }
    else if (idx < 196608) { int l = idx - 49152;  int c = l / 49152; rem = l % 49152; K = 128; N = 384; src = msg_w2 + c * 49152; }
    else if (idx < 294912) { int l = idx - 196608; int c = l / 32768; rem = l % 32768; K = 128; N = 128;
                             if (rem < 16384) src = upd_u + c * 16384;
                             else { src = upd_v + c * 16384; rem -= 16384; } }
    else if (idx < 393216) { int l = idx - 294912; int c = l / 32768; rem = l % 32768; K = 256; N = 128; src = upd_w1 + c * 32768; }
    else                   { int l = idx - 393216; int c = l / 49152; rem = l % 49152; K = 128; N = 384; src = upd_w2 + c * 49152; }
    int n = rem / K, k = rem % K;
    float val = src[k * N + n];
    ushort_t h = f2bf(val);
    dhi[idx] = h;
    dlo[idx] = f2bf(val - bf2f(h));
}

// ---------------- MFMA bf16x3 GEMM, TM x 128 tile ----------------
// f32 accuracy: A@B ~= Ah@Bh + Ah@Bl + Al@Bh (drop lo*lo, ~2^-18 rel).
// AMODE 0: A f32 MxK.  AMODE 1: A pre-split hi/lo bf16 (K-contig).
// AMODE 2: virtual A = [s | norm(vv)] (K=256; k<128 from s f32, k>=128 = ||vv|| on the fly).
// OUTMODE 0: f32, split-column (C0/C1).  OUTMODE 1: bf16 hi/lo (Chi/Clo, ld0).
// Bt hi/lo: Nc x K bf16 K-contig. 256 threads = 4 waves, each wave 32 N-cols.
template<int AMODE, int OUTMODE, int TM>
__global__ __launch_bounds__(256) void gemm64(
    const float* __restrict__ Af, const ushort_t* __restrict__ Ahi,
    const ushort_t* __restrict__ Alo, const float* __restrict__ vvp,
    const ushort_t* __restrict__ Bhi, const ushort_t* __restrict__ Blo,
    const float* __restrict__ bias,
    float* __restrict__ C0, float* __restrict__ C1,
    ushort_t* __restrict__ Chi, ushort_t* __restrict__ Clo,
    int K, int split, int ld0, int ld1, int act)
{
    constexpr int MI = TM / 16;            // m fragment tiles
    constexpr int EA = TM * 32 / 256;      // A elems per thread per k-iter (8 or 4)
    __shared__ __align__(16) ushort_t Ah[TM * 40];
    __shared__ __align__(16) ushort_t Al[TM * 40];
    __shared__ __align__(16) ushort_t Bh[128 * 40];
    __shared__ __align__(16) ushort_t Bl[128 * 40];
    const int tid = threadIdx.x;
    const int wave = tid >> 6, lane = tid & 63;
    const int row_l = lane & 15, quad = lane >> 4;
    const int wn = wave * 32;
    const int m0 = blockIdx.y * TM, n0 = blockIdx.x * 128;
    const int lrA = tid / (32 / EA);
    const int ksA = (tid % (32 / EA)) * EA;
    const int lrB = tid >> 1, ksB = (tid & 1) * 16;

    f32x4 acc[MI][2];
    #pragma unroll
    for (int i = 0; i < MI; ++i)
        #pragma unroll
        for (int j = 0; j < 2; ++j)
            #pragma unroll
            for (int r = 0; r < 4; ++r) acc[i][j][r] = 0.f;

    for (int k0 = 0; k0 < K; k0 += 32) {
        // ---- stage A ----
        if constexpr (AMODE == 1) {
            const ushort_t* ah = &Ahi[(size_t)(m0 + lrA) * K + k0 + ksA];
            const ushort_t* al = &Alo[(size_t)(m0 + lrA) * K + k0 + ksA];
            if constexpr (EA == 8) {
                *(uint4*)&Ah[lrA * 40 + ksA] = *(const uint4*)ah;
                *(uint4*)&Al[lrA * 40 + ksA] = *(const uint4*)al;
            } else {
                *(uint2*)&Ah[lrA * 40 + ksA] = *(const uint2*)ah;
                *(uint2*)&Al[lrA * 40 + ksA] = *(const uint2*)al;
            }
        } else {
            float e[EA];
            if constexpr (AMODE == 0) {
                const float* ap = &Af[(size_t)(m0 + lrA) * K + k0 + ksA];
                #pragma unroll
                for (int q = 0; q < EA / 4; ++q) {
                    float4 v = *(const float4*)(ap + q * 4);
                    e[q*4+0] = v.x; e[q*4+1] = v.y; e[q*4+2] = v.z; e[q*4+3] = v.w;
                }
            } else {   // AMODE 2
                if (k0 + ksA < 128) {
                    const float* ap = &Af[(size_t)(m0 + lrA) * 128 + k0 + ksA];
                    #pragma unroll
                    for (int q = 0; q < EA / 4; ++q) {
                        float4 v = *(const float4*)(ap + q * 4);
                        e[q*4+0] = v.x; e[q*4+1] = v.y; e[q*4+2] = v.z; e[q*4+3] = v.w;
                    }
                } else {
                    int f = k0 + ksA - 128;
                    const float* px = &vvp[(size_t)(m0 + lrA) * F + f];
                    #pragma unroll
                    for (int q = 0; q < EA / 4; ++q) {
                        float4 x = *(const float4*)(px + q * 4);
                        float4 y = *(const float4*)(px + NFC + q * 4);
                        float4 z = *(const float4*)(px + 2 * NFC + q * 4);
                        e[q*4+0] = sqrtf(x.x*x.x + y.x*y.x + z.x*z.x + 1e-15f);
                        e[q*4+1] = sqrtf(x.y*x.y + y.y*y.y + z.y*z.y + 1e-15f);
                        e[q*4+2] = sqrtf(x.z*x.z + y.z*y.z + z.z*z.z + 1e-15f);
                        e[q*4+3] = sqrtf(x.w*x.w + y.w*y.w + z.w*z.w + 1e-15f);
                    }
                }
            }
            ushort_t ph[EA], pl[EA];
            #pragma unroll
            for (int t = 0; t < EA; ++t) {
                ushort_t h = f2bf(e[t]);
                ph[t] = h; pl[t] = f2bf(e[t] - bf2f(h));
            }
            if constexpr (EA == 8) {
                *(uint4*)&Ah[lrA * 40 + ksA] = *(uint4*)ph;
                *(uint4*)&Al[lrA * 40 + ksA] = *(uint4*)pl;
            } else {
                *(uint2*)&Ah[lrA * 40 + ksA] = *(uint2*)ph;
                *(uint2*)&Al[lrA * 40 + ksA] = *(uint2*)pl;
            }
        }
        // ---- stage B (always pre-split bf16) ----
        {
            const ushort_t* bh = &Bhi[(size_t)(n0 + lrB) * K + k0 + ksB];
            const ushort_t* bl = &Blo[(size_t)(n0 + lrB) * K + k0 + ksB];
            *(uint4*)&Bh[lrB * 40 + ksB]     = *(const uint4*)bh;
            *(uint4*)&Bh[lrB * 40 + ksB + 8] = *(const uint4*)(bh + 8);
            *(uint4*)&Bl[lrB * 40 + ksB]     = *(const uint4*)bl;
            *(uint4*)&Bl[lrB * 40 + ksB + 8] = *(const uint4*)(bl + 8);
        }
        __syncthreads();
        bf16x8 ahf[MI], alf[MI], bhf[2], blf[2];
        #pragma unroll
        for (int i = 0; i < MI; ++i) {
            int ar = (i * 16 + row_l) * 40 + quad * 8;
            ahf[i] = *(const bf16x8*)&Ah[ar];
            alf[i] = *(const bf16x8*)&Al[ar];
        }
        #pragma unroll
        for (int j = 0; j < 2; ++j) {
            int br = (wn + j * 16 + row_l) * 40 + quad * 8;
            bhf[j] = *(const bf16x8*)&Bh[br];
            blf[j] = *(const bf16x8*)&Bl[br];
        }
        #pragma unroll
        for (int i = 0; i < MI; ++i)
            #pragma unroll
            for (int j = 0; j < 2; ++j) {
                acc[i][j] = __builtin_amdgcn_mfma_f32_16x16x32_bf16(ahf[i], bhf[j], acc[i][j], 0, 0, 0);
                acc[i][j] = __builtin_amdgcn_mfma_f32_16x16x32_bf16(ahf[i], blf[j], acc[i][j], 0, 0, 0);
                acc[i][j] = __builtin_amdgcn_mfma_f32_16x16x32_bf16(alf[i], bhf[j], acc[i][j], 0, 0, 0);
            }
        __syncthreads();
    }

    // ---- epilogue: D[row][col]: col = lane&15 (+tiles), row = quad*4 + r (+tiles) ----
    #pragma unroll
    for (int j = 0; j < 2; ++j) {
        int col = n0 + wn + j * 16 + row_l;
        float bval = bias ? bias[col] : 0.f;
        if constexpr (OUTMODE == 0) {
            float* Cp; int ccol, ld;
            if (col < split) { Cp = C0; ccol = col; ld = ld0; }
            else             { Cp = C1; ccol = col - split; ld = ld1; }
            #pragma unroll
            for (int i = 0; i < MI; ++i)
                #pragma unroll
                for (int r = 0; r < 4; ++r) {
                    int row = m0 + i * 16 + quad * 4 + r;
                    float v = acc[i][j][r] + bval;
                    if (act) v = silu_f(v);
                    Cp[(size_t)row * ld + ccol] = v;
                }
        } else {
            #pragma unroll
            for (int i = 0; i < MI; ++i)
                #pragma unroll
                for (int r = 0; r < 4; ++r) {
                    int row = m0 + i * 16 + quad * 4 + r;
                    float v = acc[i][j][r] + bval;
                    if (act) v = silu_f(v);
                    ushort_t h = f2bf(v);
                    Chi[(size_t)row * ld0 + col] = h;
                    Clo[(size_t)row * ld0 + col] = f2bf(v - bf2f(h));
                }
        }
    }
}

// ---------------- atom-centric message gather (atomic-free) ----------------
__global__ __launch_bounds__(128) void msg_gather(
    const float* __restrict__ phi, const float* __restrict__ rbfe,
    const float* __restrict__ envb, const float* __restrict__ unitb,
    const int* __restrict__ nbrs, const float* __restrict__ rbf_w,
    const float* __restrict__ rbf_b, const float* __restrict__ v_in,
    float* __restrict__ s, float* __restrict__ v_out,
    const int* __restrict__ sorted_eid, const int* __restrict__ offsets,
    const int* __restrict__ cnt)
{
    const int n = blockIdx.x, tid = threadIdx.x;
    float W0[N_RBF], W1[N_RBF], W2[N_RBF];
    #pragma unroll
    for (int k = 0; k < N_RBF; ++k) {
        W0[k] = rbf_w[k*3*F + tid];
        W1[k] = rbf_w[k*3*F + F + tid];
        W2[k] = rbf_w[k*3*F + 2*F + tid];
    }
    const float b0 = rbf_b[tid], b1 = rbf_b[F + tid], b2 = rbf_b[2*F + tid];
    float ds = 0.f, dvx = 0.f, dvy = 0.f, dvz = 0.f;
    const int off = offsets[n], c = cnt[n];
    for (int t = 0; t < c; ++t) {
        int e = sorted_eid[off + t];
        int j = nbrs[2*e+1];
        float ev = envb[e];
        float ux = unitb[3*e+0], uy = unitb[3*e+1], uz = unitb[3*e+2];
        float w0 = b0 * ev, w1 = b1 * ev, w2 = b2 * ev;
        #pragma unroll
        for (int k = 0; k < N_RBF; ++k) {
            float rk = rbfe[e*N_RBF + k];
            w0 += rk * W0[k]; w1 += rk * W1[k]; w2 += rk * W2[k];
        }
        const float* prow = phi + (size_t)j * 3 * F;
        float s0 = prow[tid] * w0;
        float s1 = prow[F + tid] * w1;
        float s2 = prow[2*F + tid] * w2;
        ds  += s1;
        dvx += s2*ux + s0 * v_in[(size_t)j*F + tid];
        dvy += s2*uy + s0 * v_in[NFC   + (size_t)j*F + tid];
        dvz += s2*uz + s0 * v_in[2*NFC + (size_t)j*F + tid];
    }
    size_t idx = (size_t)n * F + tid;
    s[idx] += ds;
    v_out[idx]         = v_in[idx]         + dvx;
    v_out[NFC + idx]   = v_in[NFC + idx]   + dvy;
    v_out[2*NFC + idx] = v_in[2*NFC + idx] + dvz;
}

// ---------------- final conv update ----------------
__global__ __launch_bounds__(256) void finupd_kernel(
    const float* __restrict__ uv, const float* __restrict__ vv,
    const float* __restrict__ a, float* __restrict__ s, float* __restrict__ v)
{
    size_t idx = (size_t)blockIdx.x * 256 + threadIdx.x;   // < N_ATOMS*F
    int n = (int)(idx >> 7), f = (int)(idx & 127);
    float ux = uv[idx], uy = uv[NFC + idx], uz = uv[2*NFC + idx];
    float wx = vv[idx], wy = vv[NFC + idx], wz = vv[2*NFC + idx];
    float dot = ux*wx + uy*wy + uz*wz;
    const float* arow = a + (size_t)n * 3 * F;
    s[idx] += dot * arow[F + f] + arow[2*F + f];
    float avv = arow[f];
    v[idx]         += ux * avv;
    v[NFC + idx]   += uy * avv;
    v[2*NFC + idx] += uz * avv;
}

// ---------------- fused readout: silu(s@w1+b1)@w2+b2 -> segment_sum ----------------
// 4 waves/block, 1 atom/wave. ro_w1 (128x64) in LDS.
__global__ __launch_bounds__(256) void readout_fused(
    const float* __restrict__ s, const float* __restrict__ w1,
    const float* __restrict__ b1, const float* __restrict__ w2,
    const float* __restrict__ b2, const int* __restrict__ mol,
    float* __restrict__ out)
{
    __shared__ float w1s[128 * 64];    // [k][h]
    __shared__ float srow[4][128];
    int tid = threadIdx.x;
    for (int i = tid; i < 128 * 64; i += 256) w1s[i] = w1[i];
    int wave = tid >> 6, lane = tid & 63;
    int n = blockIdx.x * 4 + wave;     // grid sized exactly N_ATOMS/4
    srow[wave][lane]      = s[(size_t)n * F + lane];
    srow[wave][lane + 64] = s[(size_t)n * F + 64 + lane];
    __syncthreads();
    float acc = 0.f;
    #pragma unroll 4
    for (int k = 0; k < 128; ++k)
        acc += srow[wave][k] * w1s[k * 64 + lane];
    float val = silu_f(acc + b1[lane]) * w2[lane];
    #pragma unroll
    for (int offd = 32; offd > 0; offd >>= 1) val += __shfl_down(val, offd);
    if (lane == 0) atomicAdd(&out[mol[n]], val + b2[0]);
}

extern "C" void kernel_launch(void* const* d_in, const int* in_sizes, int n_in,
                              void* d_out, int out_size, void* d_ws, size_t ws_size,
                              hipStream_t stream)
{
    const float* xyz    = (const float*)d_in[0];
    const float* emb    = (const float*)d_in[1];
    const float* msg_w1 = (const float*)d_in[2];
    const float* msg_b1 = (const float*)d_in[3];
    const float* msg_w2 = (const float*)d_in[4];
    const float* msg_b2 = (const float*)d_in[5];
    const float* rbf_w  = (const float*)d_in[6];
    const float* rbf_b  = (const float*)d_in[7];
    const float* upd_u  = (const float*)d_in[8];
    const float* upd_v  = (const float*)d_in[9];
    const float* upd_w1 = (const float*)d_in[10];
    const float* upd_b1 = (const float*)d_in[11];
    const float* upd_w2 = (const float*)d_in[12];
    const float* upd_b2 = (const float*)d_in[13];
    const float* ro_w1  = (const float*)d_in[14];
    const float* ro_b1  = (const float*)d_in[15];
    const float* ro_w2  = (const float*)d_in[16];
    const float* ro_b2  = (const float*)d_in[17];
    const int*   z      = (const int*)d_in[18];
    const int*   nbrs   = (const int*)d_in[19];
    const int*   molidx = (const int*)d_in[20];
    float* out = (float*)d_out;

    float* ws = (float*)d_ws;
    size_t off = 0;
    auto alloc = [&](size_t n) { float* p = ws + off; off += n; return p; };
    float* s_buf   = alloc(NFC);
    float* v1_buf  = alloc(3 * NFC);
    float* v2_buf  = alloc(3 * NFC);
    float* uv_buf  = alloc(3 * NFC);
    float* vv_buf  = alloc(3 * NFC);
    float* phi_buf = alloc(3 * NFC);
    ushort_t* hhi  = (ushort_t*)alloc(NFC / 2);   // hidden activations, bf16 hi/lo
    ushort_t* hlo  = (ushort_t*)alloc(NFC / 2);
    float* rbfe    = alloc((size_t)N_EDGES * N_RBF);
    float* envb    = alloc(N_EDGES);
    float* unitb   = alloc((size_t)N_EDGES * 3);
    ushort_t* wbf_hi = (ushort_t*)alloc(WPREP_TOTAL / 2 + 64);
    ushort_t* wbf_lo = (ushort_t*)alloc(WPREP_TOTAL / 2 + 64);
    int* cnt        = (int*)alloc(N_ATOMS);
    int* cursor     = (int*)alloc(N_ATOMS);
    int* offsets    = (int*)alloc(N_ATOMS);
    int* sorted_eid = (int*)alloc(N_EDGES);

    // bf16 weight sub-offsets (elements, see wprep_kernel)
    const size_t oW1 = 0, oW2 = 49152, oUV = 196608, oU1 = 294912, oU2 = 393216;

    hipMemsetAsync(out, 0, sizeof(float) * N_MOLS, stream);
    hipMemsetAsync(v1_buf, 0, sizeof(float) * 3 * NFC, stream);
    hipMemsetAsync(cnt, 0, sizeof(int) * 2 * N_ATOMS, stream);   // cnt + cursor adjacent

    geom_kernel<<<dim3((N_EDGES + 255) / 256), dim3(256), 0, stream>>>(
        xyz, nbrs, rbfe, envb, unitb, cnt);
    scan_kernel<<<dim3(1), dim3(1024), 0, stream>>>(cnt, offsets);
    scatter_kernel<<<dim3((N_EDGES + 255) / 256), dim3(256), 0, stream>>>(
        nbrs, envb, offsets, cursor, sorted_eid);
    embed_kernel<<<dim3(N_ATOMS * F / 256), dim3(256), 0, stream>>>(emb, z, s_buf);
    wprep_kernel<<<dim3((WPREP_TOTAL + 255) / 256), dim3(256), 0, stream>>>(
        msg_w1, msg_w2, upd_u, upd_v, upd_w1, upd_w2, wbf_hi, wbf_lo);

    float* vin = v1_buf;
    float* vout = v2_buf;
    for (int i = 0; i < 3; ++i) {
        // h = silu(s@W1+b1) -> bf16 hi/lo  (TM=32: 252 blocks)
        gemm64<0, 1, 32><<<dim3(1, NP/32), dim3(256), 0, stream>>>(
            s_buf, nullptr, nullptr, nullptr,
            wbf_hi + oW1 + (size_t)i*16384, wbf_lo + oW1 + (size_t)i*16384,
            msg_b1 + (size_t)i*F, nullptr, nullptr, hhi, hlo,
            128, 0, F, 0, 1);
        // phi = h@W2+b2  (378 blocks)
        gemm64<1, 0, 64><<<dim3(3, NP/64), dim3(256), 0, stream>>>(
            nullptr, hhi, hlo, nullptr,
            wbf_hi + oW2 + (size_t)i*49152, wbf_lo + oW2 + (size_t)i*49152,
            msg_b2 + (size_t)i*3*F, phi_buf, phi_buf, nullptr, nullptr,
            128, 3*F, 3*F, 3*F, 0);
        // atomic-free message gather: s += ds in place; vout = vin + dv
        msg_gather<<<dim3(N_ATOMS), dim3(128), 0, stream>>>(
            phi_buf, rbfe, envb, unitb, nbrs,
            rbf_w + (size_t)i*N_RBF*3*F, rbf_b + (size_t)i*3*F,
            vin, s_buf, vout, sorted_eid, offsets, cnt);
        // fused u_v|v_v: one GEMM over M=3*NP, split-column epilogue (756 blocks)
        gemm64<0, 0, 64><<<dim3(2, 3*NP/64), dim3(256), 0, stream>>>(
            vout, nullptr, nullptr, nullptr,
            wbf_hi + oUV + (size_t)i*32768, wbf_lo + oUV + (size_t)i*32768,
            nullptr, uv_buf, vv_buf, nullptr, nullptr,
            128, F, F, F, 0);
        // h = silu([s|norm(vv)]@W1+b1) with stack fused into staging (252 blocks)
        gemm64<2, 1, 32><<<dim3(1, NP/32), dim3(256), 0, stream>>>(
            s_buf, nullptr, nullptr, vv_buf,
            wbf_hi + oU1 + (size_t)i*32768, wbf_lo + oU1 + (size_t)i*32768,
            upd_b1 + (size_t)i*F, nullptr, nullptr, hhi, hlo,
            256, 0, F, 0, 1);
        // a = h@W2+b2 -> phi_buf (378 blocks)
        gemm64<1, 0, 64><<<dim3(3, NP/64), dim3(256), 0, stream>>>(
            nullptr, hhi, hlo, nullptr,
            wbf_hi + oU2 + (size_t)i*49152, wbf_lo + oU2 + (size_t)i*49152,
            upd_b2 + (size_t)i*3*F, phi_buf, phi_buf, nullptr, nullptr,
            128, 3*F, 3*F, 3*F, 0);
        finupd_kernel<<<dim3(N_ATOMS * F / 256), dim3(256), 0, stream>>>(
            uv_buf, vv_buf, phi_buf, s_buf, vout);
        float* tmp = vin; vin = vout; vout = tmp;
    }

    readout_fused<<<dim3(N_ATOMS / 4), dim3(256), 0, stream>>>(
        s_buf, ro_w1, ro_b1, ro_w2, ro_b2, molidx, out);
}

// Round 7
// 463.642 us; speedup vs baseline: 1.4879x; 1.0730x over previous
//
#include <hip/hip_runtime.h>

static constexpr int F = 128;
static constexpr int N_RBF = 20;
static constexpr int N_ATOMS = 8000;
static constexpr int NP = 8064;          // padded to 128 (pad rows hold harness poison = tiny normal floats, benign)
static constexpr int N_EDGES = 160000;
static constexpr int N_MOLS = 100;
static constexpr float CUTOFF = 5.0f;
static constexpr size_t NFC = (size_t)NP * F;   // padded plane-equivalent size (buffer sizing)
static constexpr int REC = 28;           // packed edge record: j, ev, ux,uy,uz, rbf[20], pad[3]
#define PIF 3.14159265358979323846f

typedef __attribute__((ext_vector_type(8))) short bf16x8;
typedef __attribute__((ext_vector_type(4))) float f32x4;
typedef unsigned short ushort_t;
typedef unsigned int uint_t;

__device__ __forceinline__ float silu_f(float x) { return x / (1.f + __expf(-x)); }

__device__ __forceinline__ ushort_t f2bf(float x) {   // round-to-nearest-even
    union { float f; uint_t u; } v; v.f = x;
    uint_t r = v.u + 0x7fffu + ((v.u >> 16) & 1u);
    return (ushort_t)(r >> 16);
}
__device__ __forceinline__ float bf2f(ushort_t h) {
    union { uint_t u; float f; } v; v.u = ((uint_t)h) << 16; return v.f;
}

// ---------------- edge geometry + live-edge histogram ----------------
__global__ __launch_bounds__(256) void geom_kernel(
    const float* __restrict__ xyz, const int* __restrict__ nbrs,
    float* __restrict__ rbfe, float* __restrict__ envb, float* __restrict__ unitb,
    int* __restrict__ cnt)
{
    int e = blockIdx.x * 256 + threadIdx.x;
    if (e >= N_EDGES) return;
    int i0 = nbrs[2*e+0], i1 = nbrs[2*e+1];
    float dx = xyz[3*i1+0] - xyz[3*i0+0];
    float dy = xyz[3*i1+1] - xyz[3*i0+1];
    float dz = xyz[3*i1+2] - xyz[3*i0+2];
    float d  = sqrtf(dx*dx + dy*dy + dz*dz);
    float inv = 1.f / d;
    unitb[3*e+0] = dx*inv; unitb[3*e+1] = dy*inv; unitb[3*e+2] = dz*inv;
    float ev = (d <= CUTOFF) ? 0.5f*(cosf(PIF*d/CUTOFF) + 1.f) : 0.f;
    envb[e] = ev;
    float base = PIF*d/CUTOFF;
    float sc = inv * ev;   // fold env into rbf (w_s = (rbf*env)@W + b*env)
    #pragma unroll
    for (int k = 0; k < N_RBF; ++k)
        rbfe[e*N_RBF + k] = sinf((float)(k+1)*base) * sc;
    if (ev > 0.f) atomicAdd(&cnt[i0], 1);
}

// ---------------- exclusive scan of 8000 counters (single block) ----------------
__global__ __launch_bounds__(1024) void scan_kernel(
    const int* __restrict__ cnt, int* __restrict__ offsets)
{
    __shared__ int sums[1024];
    int tid = threadIdx.x;
    int base = tid * 8;
    int local[8]; int s = 0;
    #pragma unroll
    for (int i = 0; i < 8; ++i) {
        int idx = base + i;
        local[i] = (idx < N_ATOMS) ? cnt[idx] : 0;
        s += local[i];
    }
    sums[tid] = s;
    __syncthreads();
    for (int d = 1; d < 1024; d <<= 1) {
        int v = (tid >= d) ? sums[tid - d] : 0;
        __syncthreads();
        sums[tid] += v;
        __syncthreads();
    }
    int ex = (tid == 0) ? 0 : sums[tid - 1];
    #pragma unroll
    for (int i = 0; i < 8; ++i) {
        int idx = base + i;
        if (idx < N_ATOMS) { offsets[idx] = ex; ex += local[i]; }
    }
}

// ---------------- scatter: build packed records for live edges (sorted by target) ----------------
__global__ __launch_bounds__(256) void scatter_kernel(
    const int* __restrict__ nbrs, const float* __restrict__ envb,
    const float* __restrict__ rbfe, const float* __restrict__ unitb,
    const int* __restrict__ offsets, int* __restrict__ cursor,
    float* __restrict__ rec)
{
    int e = blockIdx.x * 256 + threadIdx.x;
    if (e >= N_EDGES) return;
    float ev = envb[e];
    if (ev <= 0.f) return;
    int tgt = nbrs[2*e+0];
    int pos = offsets[tgt] + atomicAdd(&cursor[tgt], 1);
    float* r = rec + (size_t)pos * REC;
    r[0] = __int_as_float(nbrs[2*e+1]);
    r[1] = ev;
    r[2] = unitb[3*e+0]; r[3] = unitb[3*e+1]; r[4] = unitb[3*e+2];
    #pragma unroll
    for (int k = 0; k < N_RBF; ++k) r[5 + k] = rbfe[e*N_RBF + k];
}

// ---------------- s = emb_table[z] ----------------
__global__ __launch_bounds__(256) void embed_kernel(
    const float* __restrict__ emb, const int* __restrict__ z, float* __restrict__ s)
{
    int idx = blockIdx.x * 256 + threadIdx.x;   // grid sized exactly N_ATOMS*F
    int n = idx >> 7, f = idx & 127;
    s[idx] = emb[z[n]*F + f];
}

// ---------------- weight prep: transpose + f32 -> (bf16 hi, bf16 lo) ----------------
// dst layout (bf16, [n][k] row-major K-contig), same offsets for hi and lo buffers:
//   W1t  3x(128n x 128k) @ 0        src msg_w1 (128k x 128n)
//   W2t  3x(384n x 128k) @ 49152    src msg_w2
//   UVt  3x(256n x 128k) @ 196608   src upd_u (n 0..127) | upd_v (n 128..255)
//   U1t  3x(128n x 256k) @ 294912   src upd_w1 (256k x 128n)
//   U2t  3x(384n x 128k) @ 393216   src upd_w2
static constexpr int WPREP_TOTAL = 540672;
__global__ __launch_bounds__(256) void wprep_kernel(
    const float* __restrict__ msg_w1, const float* __restrict__ msg_w2,
    const float* __restrict__ upd_u,  const float* __restrict__ upd_v,
    const float* __restrict__ upd_w1, const float* __restrict__ upd_w2,
    ushort_t* __restrict__ dhi, ushort_t* __restrict__ dlo)
{
    int idx = blockIdx.x * 256 + threadIdx.x;
    if (idx >= WPREP_TOTAL) return;
    const float* src; int K, N, rem;
    if (idx < 49152)       { int l = idx;          int c = l / 16384; rem = l % 16384; K = 128; N = 128; src = msg_w1 + c * 16384; }
    else if (idx < 196608) { int l = idx - 49152;  int c = l / 49152; rem = l % 49152; K = 128; N = 384; src = msg_w2 + c * 49152; }
    else if (idx < 294912) { int l = idx - 196608; int c = l / 32768; rem = l % 32768; K = 128; N = 128;
                             if (rem < 16384) src = upd_u + c * 16384;
                             else { src = upd_v + c * 16384; rem -= 16384; } }
    else if (idx < 393216) { int l = idx - 294912; int c = l / 32768; rem = l % 32768; K = 256; N = 128; src = upd_w1 + c * 32768; }
    else                   { int l = idx - 393216; int c = l / 49152; rem = l % 49152; K = 128; N = 384; src = upd_w2 + c * 49152; }
    int n = rem / K, k = rem % K;
    float val = src[k * N + n];
    ushort_t h = f2bf(val);
    dhi[idx] = h;
    dlo[idx] = f2bf(val - bf2f(h));
}

// ---------------- MFMA bf16x3 GEMM, TM x 128 tile ----------------
// f32 accuracy: A@B ~= Ah@Bh + Ah@Bl + Al@Bh (drop lo*lo, ~2^-18 rel).
// AMODE 0: A f32 MxK.  AMODE 1: A pre-split hi/lo bf16 (K-contig).
// AMODE 2: virtual A = [s | norm(vv)] (K=256; k<128 from s f32, k>=128 = ||vv|| on the fly;
//          vv layout [n][3][f]).
// OUTMODE 0: f32, split-column (C0/C1).  OUTMODE 1: bf16 hi/lo (Chi/Clo, ld0).
// Bt hi/lo: Nc x K bf16 K-contig. 256 threads = 4 waves, each wave 32 N-cols.
template<int AMODE, int OUTMODE, int TM>
__global__ __launch_bounds__(256) void gemm64(
    const float* __restrict__ Af, const ushort_t* __restrict__ Ahi,
    const ushort_t* __restrict__ Alo, const float* __restrict__ vvp,
    const ushort_t* __restrict__ Bhi, const ushort_t* __restrict__ Blo,
    const float* __restrict__ bias,
    float* __restrict__ C0, float* __restrict__ C1,
    ushort_t* __restrict__ Chi, ushort_t* __restrict__ Clo,
    int K, int split, int ld0, int ld1, int act)
{
    constexpr int MI = TM / 16;            // m fragment tiles
    constexpr int EA = TM * 32 / 256;      // A elems per thread per k-iter (8 or 4)
    __shared__ __align__(16) ushort_t Ah[TM * 40];
    __shared__ __align__(16) ushort_t Al[TM * 40];
    __shared__ __align__(16) ushort_t Bh[128 * 40];
    __shared__ __align__(16) ushort_t Bl[128 * 40];
    const int tid = threadIdx.x;
    const int wave = tid >> 6, lane = tid & 63;
    const int row_l = lane & 15, quad = lane >> 4;
    const int wn = wave * 32;
    const int m0 = blockIdx.y * TM, n0 = blockIdx.x * 128;
    const int lrA = tid / (32 / EA);
    const int ksA = (tid % (32 / EA)) * EA;
    const int lrB = tid >> 1, ksB = (tid & 1) * 16;

    f32x4 acc[MI][2];
    #pragma unroll
    for (int i = 0; i < MI; ++i)
        #pragma unroll
        for (int j = 0; j < 2; ++j)
            #pragma unroll
            for (int r = 0; r < 4; ++r) acc[i][j][r] = 0.f;

    for (int k0 = 0; k0 < K; k0 += 32) {
        // ---- stage A ----
        if constexpr (AMODE == 1) {
            const ushort_t* ah = &Ahi[(size_t)(m0 + lrA) * K + k0 + ksA];
            const ushort_t* al = &Alo[(size_t)(m0 + lrA) * K + k0 + ksA];
            if constexpr (EA == 8) {
                *(uint4*)&Ah[lrA * 40 + ksA] = *(const uint4*)ah;
                *(uint4*)&Al[lrA * 40 + ksA] = *(const uint4*)al;
            } else {
                *(uint2*)&Ah[lrA * 40 + ksA] = *(const uint2*)ah;
                *(uint2*)&Al[lrA * 40 + ksA] = *(const uint2*)al;
            }
        } else {
            float e[EA];
            if constexpr (AMODE == 0) {
                const float* ap = &Af[(size_t)(m0 + lrA) * K + k0 + ksA];
                #pragma unroll
                for (int q = 0; q < EA / 4; ++q) {
                    float4 v = *(const float4*)(ap + q * 4);
                    e[q*4+0] = v.x; e[q*4+1] = v.y; e[q*4+2] = v.z; e[q*4+3] = v.w;
                }
            } else {   // AMODE 2
                if (k0 + ksA < 128) {
                    const float* ap = &Af[(size_t)(m0 + lrA) * 128 + k0 + ksA];
                    #pragma unroll
                    for (int q = 0; q < EA / 4; ++q) {
                        float4 v = *(const float4*)(ap + q * 4);
                        e[q*4+0] = v.x; e[q*4+1] = v.y; e[q*4+2] = v.z; e[q*4+3] = v.w;
                    }
                } else {
                    int f = k0 + ksA - 128;
                    const float* px = &vvp[((size_t)(m0 + lrA) * 3) * F + f];   // [n][3][f]
                    #pragma unroll
                    for (int q = 0; q < EA / 4; ++q) {
                        float4 x = *(const float4*)(px + q * 4);
                        float4 y = *(const float4*)(px + F + q * 4);
                        float4 z = *(const float4*)(px + 2 * F + q * 4);
                        e[q*4+0] = sqrtf(x.x*x.x + y.x*y.x + z.x*z.x + 1e-15f);
                        e[q*4+1] = sqrtf(x.y*x.y + y.y*y.y + z.y*z.y + 1e-15f);
                        e[q*4+2] = sqrtf(x.z*x.z + y.z*y.z + z.z*z.z + 1e-15f);
                        e[q*4+3] = sqrtf(x.w*x.w + y.w*y.w + z.w*z.w + 1e-15f);
                    }
                }
            }
            ushort_t ph[EA], pl[EA];
            #pragma unroll
            for (int t = 0; t < EA; ++t) {
                ushort_t h = f2bf(e[t]);
                ph[t] = h; pl[t] = f2bf(e[t] - bf2f(h));
            }
            if constexpr (EA == 8) {
                *(uint4*)&Ah[lrA * 40 + ksA] = *(uint4*)ph;
                *(uint4*)&Al[lrA * 40 + ksA] = *(uint4*)pl;
            } else {
                *(uint2*)&Ah[lrA * 40 + ksA] = *(uint2*)ph;
                *(uint2*)&Al[lrA * 40 + ksA] = *(uint2*)pl;
            }
        }
        // ---- stage B (always pre-split bf16) ----
        {
            const ushort_t* bh = &Bhi[(size_t)(n0 + lrB) * K + k0 + ksB];
            const ushort_t* bl = &Blo[(size_t)(n0 + lrB) * K + k0 + ksB];
            *(uint4*)&Bh[lrB * 40 + ksB]     = *(const uint4*)bh;
            *(uint4*)&Bh[lrB * 40 + ksB + 8] = *(const uint4*)(bh + 8);
            *(uint4*)&Bl[lrB * 40 + ksB]     = *(const uint4*)bl;
            *(uint4*)&Bl[lrB * 40 + ksB + 8] = *(const uint4*)(bl + 8);
        }
        __syncthreads();
        bf16x8 ahf[MI], alf[MI], bhf[2], blf[2];
        #pragma unroll
        for (int i = 0; i < MI; ++i) {
            int ar = (i * 16 + row_l) * 40 + quad * 8;
            ahf[i] = *(const bf16x8*)&Ah[ar];
            alf[i] = *(const bf16x8*)&Al[ar];
        }
        #pragma unroll
        for (int j = 0; j < 2; ++j) {
            int br = (wn + j * 16 + row_l) * 40 + quad * 8;
            bhf[j] = *(const bf16x8*)&Bh[br];
            blf[j] = *(const bf16x8*)&Bl[br];
        }
        #pragma unroll
        for (int i = 0; i < MI; ++i)
            #pragma unroll
            for (int j = 0; j < 2; ++j) {
                acc[i][j] = __builtin_amdgcn_mfma_f32_16x16x32_bf16(ahf[i], bhf[j], acc[i][j], 0, 0, 0);
                acc[i][j] = __builtin_amdgcn_mfma_f32_16x16x32_bf16(ahf[i], blf[j], acc[i][j], 0, 0, 0);
                acc[i][j] = __builtin_amdgcn_mfma_f32_16x16x32_bf16(alf[i], bhf[j], acc[i][j], 0, 0, 0);
            }
        __syncthreads();
    }

    // ---- epilogue: D[row][col]: col = lane&15 (+tiles), row = quad*4 + r (+tiles) ----
    #pragma unroll
    for (int j = 0; j < 2; ++j) {
        int col = n0 + wn + j * 16 + row_l;
        float bval = bias ? bias[col] : 0.f;
        if constexpr (OUTMODE == 0) {
            float* Cp; int ccol, ld;
            if (col < split) { Cp = C0; ccol = col; ld = ld0; }
            else             { Cp = C1; ccol = col - split; ld = ld1; }
            #pragma unroll
            for (int i = 0; i < MI; ++i)
                #pragma unroll
                for (int r = 0; r < 4; ++r) {
                    int row = m0 + i * 16 + quad * 4 + r;
                    float v = acc[i][j][r] + bval;
                    if (act) v = silu_f(v);
                    Cp[(size_t)row * ld + ccol] = v;
                }
        } else {
            #pragma unroll
            for (int i = 0; i < MI; ++i)
                #pragma unroll
                for (int r = 0; r < 4; ++r) {
                    int row = m0 + i * 16 + quad * 4 + r;
                    float v = acc[i][j][r] + bval;
                    if (act) v = silu_f(v);
                    ushort_t h = f2bf(v);
                    Chi[(size_t)row * ld0 + col] = h;
                    Clo[(size_t)row * ld0 + col] = f2bf(v - bf2f(h));
                }
        }
    }
}

// ---------------- atom-centric message gather (atomic-free, packed records) ----------------
// v layout: [n][3][f] (1536 B contiguous per atom -> single-region neighbor gather).
__global__ __launch_bounds__(128) void msg_gather(
    const float* __restrict__ phi, const float* __restrict__ rec,
    const float* __restrict__ rbf_w, const float* __restrict__ rbf_b,
    const float* __restrict__ v_in, float* __restrict__ s,
    float* __restrict__ v_out, const int* __restrict__ offsets,
    const int* __restrict__ cnt)
{
    const int n = blockIdx.x, tid = threadIdx.x;
    float W0[N_RBF], W1[N_RBF], W2[N_RBF];
    #pragma unroll
    for (int k = 0; k < N_RBF; ++k) {
        W0[k] = rbf_w[k*3*F + tid];
        W1[k] = rbf_w[k*3*F + F + tid];
        W2[k] = rbf_w[k*3*F + 2*F + tid];
    }
    const float b0 = rbf_b[tid], b1 = rbf_b[F + tid], b2 = rbf_b[2*F + tid];
    float ds = 0.f, dvx = 0.f, dvy = 0.f, dvz = 0.f;
    const int off = offsets[n], c = cnt[n];
    const float* r = rec + (size_t)off * REC;
    #pragma unroll 2
    for (int t = 0; t < c; ++t, r += REC) {
        int j = __float_as_int(r[0]);
        float ev = r[1];
        float ux = r[2], uy = r[3], uz = r[4];
        float w0 = b0 * ev, w1 = b1 * ev, w2 = b2 * ev;
        #pragma unroll
        for (int k = 0; k < N_RBF; ++k) {
            float rk = r[5 + k];
            w0 += rk * W0[k]; w1 += rk * W1[k]; w2 += rk * W2[k];
        }
        const float* prow = phi + (size_t)j * 3 * F;
        const float* vrow = v_in + (size_t)j * 3 * F;
        float s0 = prow[tid] * w0;
        float s1 = prow[F + tid] * w1;
        float s2 = prow[2*F + tid] * w2;
        ds  += s1;
        dvx += s2*ux + s0 * vrow[tid];
        dvy += s2*uy + s0 * vrow[F + tid];
        dvz += s2*uz + s0 * vrow[2*F + tid];
    }
    s[(size_t)n * F + tid] += ds;
    size_t vb = (size_t)n * 3 * F + tid;
    v_out[vb]         = v_in[vb]         + dvx;
    v_out[vb + F]     = v_in[vb + F]     + dvy;
    v_out[vb + 2*F]   = v_in[vb + 2*F]   + dvz;
}

// ---------------- final conv update (v layout [n][3][f]) ----------------
__global__ __launch_bounds__(256) void finupd_kernel(
    const float* __restrict__ uv, const float* __restrict__ vv,
    const float* __restrict__ a, float* __restrict__ s, float* __restrict__ v)
{
    size_t idx = (size_t)blockIdx.x * 256 + threadIdx.x;   // < N_ATOMS*F
    int n = (int)(idx >> 7), f = (int)(idx & 127);
    size_t vb = (size_t)n * 3 * F + f;
    float ux = uv[vb], uy = uv[vb + F], uz = uv[vb + 2*F];
    float wx = vv[vb], wy = vv[vb + F], wz = vv[vb + 2*F];
    float dot = ux*wx + uy*wy + uz*wz;
    const float* arow = a + (size_t)n * 3 * F;
    s[idx] += dot * arow[F + f] + arow[2*F + f];
    float avv = arow[f];
    v[vb]        += ux * avv;
    v[vb + F]    += uy * avv;
    v[vb + 2*F]  += uz * avv;
}

// ---------------- fused readout v2: 250 blocks x 32 atoms, w1 transposed in LDS ----------------
__global__ __launch_bounds__(256) void readout_fused(
    const float* __restrict__ s, const float* __restrict__ w1,
    const float* __restrict__ b1, const float* __restrict__ w2,
    const float* __restrict__ b2, const int* __restrict__ mol,
    float* __restrict__ out)
{
    __shared__ float w1t[64 * 128];       // [h][k]
    __shared__ float srow[4][4][128];     // [wave][atom][k]
    int tid = threadIdx.x;
    for (int i = tid; i < 64 * 128; i += 256)
        w1t[i] = w1[(i & 127) * 64 + (i >> 7)];
    int wave = tid >> 6, lane = tid & 63;
    float b1v = b1[lane], w2v = w2[lane];
    int nbase = blockIdx.x * 32 + wave * 8;    // grid 250, 32 atoms/block, 8/wave
    __syncthreads();
    #pragma unroll
    for (int g = 0; g < 2; ++g) {
        int n0 = nbase + g * 4;
        #pragma unroll
        for (int aa = 0; aa < 4; ++aa) {
            srow[wave][aa][lane]      = s[(size_t)(n0 + aa) * F + lane];
            srow[wave][aa][64 + lane] = s[(size_t)(n0 + aa) * F + 64 + lane];
        }
        __syncthreads();
        float acc[4] = {0.f, 0.f, 0.f, 0.f};
        for (int k = 0; k < 128; k += 4) {
            float4 w = *(const float4*)&w1t[lane * 128 + k];
            #pragma unroll
            for (int aa = 0; aa < 4; ++aa) {
                float4 sv = *(const float4*)&srow[wave][aa][k];
                acc[aa] += sv.x * w.x + sv.y * w.y + sv.z * w.z + sv.w * w.w;
            }
        }
        #pragma unroll
        for (int aa = 0; aa < 4; ++aa) {
            float val = silu_f(acc[aa] + b1v) * w2v;
            #pragma unroll
            for (int offd = 32; offd > 0; offd >>= 1) val += __shfl_down(val, offd);
            if (lane == 0) atomicAdd(&out[mol[n0 + aa]], val + b2[0]);
        }
        __syncthreads();
    }
}

extern "C" void kernel_launch(void* const* d_in, const int* in_sizes, int n_in,
                              void* d_out, int out_size, void* d_ws, size_t ws_size,
                              hipStream_t stream)
{
    const float* xyz    = (const float*)d_in[0];
    const float* emb    = (const float*)d_in[1];
    const float* msg_w1 = (const float*)d_in[2];
    const float* msg_b1 = (const float*)d_in[3];
    const float* msg_w2 = (const float*)d_in[4];
    const float* msg_b2 = (const float*)d_in[5];
    const float* rbf_w  = (const float*)d_in[6];
    const float* rbf_b  = (const float*)d_in[7];
    const float* upd_u  = (const float*)d_in[8];
    const float* upd_v  = (const float*)d_in[9];
    const float* upd_w1 = (const float*)d_in[10];
    const float* upd_b1 = (const float*)d_in[11];
    const float* upd_w2 = (const float*)d_in[12];
    const float* upd_b2 = (const float*)d_in[13];
    const float* ro_w1  = (const float*)d_in[14];
    const float* ro_b1  = (const float*)d_in[15];
    const float* ro_w2  = (const float*)d_in[16];
    const float* ro_b2  = (const float*)d_in[17];
    const int*   z      = (const int*)d_in[18];
    const int*   nbrs   = (const int*)d_in[19];
    const int*   molidx = (const int*)d_in[20];
    float* out = (float*)d_out;

    float* ws = (float*)d_ws;
    size_t off = 0;
    auto alloc = [&](size_t n) { float* p = ws + off; off += n; return p; };
    float* s_buf   = alloc(NFC);
    float* v1_buf  = alloc(3 * NFC);       // [n][3][f]
    float* v2_buf  = alloc(3 * NFC);
    float* uv_buf  = alloc(3 * NFC);
    float* vv_buf  = alloc(3 * NFC);
    float* phi_buf = alloc(3 * NFC);
    ushort_t* hhi  = (ushort_t*)alloc(NFC / 2);   // hidden activations, bf16 hi/lo
    ushort_t* hlo  = (ushort_t*)alloc(NFC / 2);
    float* rbfe    = alloc((size_t)N_EDGES * N_RBF);
    float* envb    = alloc(N_EDGES);
    float* unitb   = alloc((size_t)N_EDGES * 3);
    float* edgerec = alloc((size_t)N_EDGES * REC);
    ushort_t* wbf_hi = (ushort_t*)alloc(WPREP_TOTAL / 2 + 64);
    ushort_t* wbf_lo = (ushort_t*)alloc(WPREP_TOTAL / 2 + 64);
    int* cnt        = (int*)alloc(N_ATOMS);
    int* cursor     = (int*)alloc(N_ATOMS);
    int* offsets    = (int*)alloc(N_ATOMS);

    // bf16 weight sub-offsets (elements, see wprep_kernel)
    const size_t oW1 = 0, oW2 = 49152, oUV = 196608, oU1 = 294912, oU2 = 393216;

    hipMemsetAsync(out, 0, sizeof(float) * N_MOLS, stream);
    hipMemsetAsync(v1_buf, 0, sizeof(float) * 3 * NFC, stream);
    hipMemsetAsync(cnt, 0, sizeof(int) * 2 * N_ATOMS, stream);   // cnt + cursor adjacent

    geom_kernel<<<dim3((N_EDGES + 255) / 256), dim3(256), 0, stream>>>(
        xyz, nbrs, rbfe, envb, unitb, cnt);
    scan_kernel<<<dim3(1), dim3(1024), 0, stream>>>(cnt, offsets);
    scatter_kernel<<<dim3((N_EDGES + 255) / 256), dim3(256), 0, stream>>>(
        nbrs, envb, rbfe, unitb, offsets, cursor, edgerec);
    embed_kernel<<<dim3(N_ATOMS * F / 256), dim3(256), 0, stream>>>(emb, z, s_buf);
    wprep_kernel<<<dim3((WPREP_TOTAL + 255) / 256), dim3(256), 0, stream>>>(
        msg_w1, msg_w2, upd_u, upd_v, upd_w1, upd_w2, wbf_hi, wbf_lo);

    float* vin = v1_buf;
    float* vout = v2_buf;
    for (int i = 0; i < 3; ++i) {
        // h = silu(s@W1+b1) -> bf16 hi/lo  (TM=32: 252 blocks)
        gemm64<0, 1, 32><<<dim3(1, NP/32), dim3(256), 0, stream>>>(
            s_buf, nullptr, nullptr, nullptr,
            wbf_hi + oW1 + (size_t)i*16384, wbf_lo + oW1 + (size_t)i*16384,
            msg_b1 + (size_t)i*F, nullptr, nullptr, hhi, hlo,
            128, 0, F, 0, 1);
        // phi = h@W2+b2  (378 blocks)
        gemm64<1, 0, 64><<<dim3(3, NP/64), dim3(256), 0, stream>>>(
            nullptr, hhi, hlo, nullptr,
            wbf_hi + oW2 + (size_t)i*49152, wbf_lo + oW2 + (size_t)i*49152,
            msg_b2 + (size_t)i*3*F, phi_buf, phi_buf, nullptr, nullptr,
            128, 3*F, 3*F, 3*F, 0);
        // atomic-free message gather: s += ds in place; vout = vin + dv
        msg_gather<<<dim3(N_ATOMS), dim3(128), 0, stream>>>(
            phi_buf, edgerec, rbf_w + (size_t)i*N_RBF*3*F, rbf_b + (size_t)i*3*F,
            vin, s_buf, vout, offsets, cnt);
        // fused u_v|v_v: one GEMM over M=3*NP rows ([n][3] row order), split-column (756 blocks)
        gemm64<0, 0, 64><<<dim3(2, 3*NP/64), dim3(256), 0, stream>>>(
            vout, nullptr, nullptr, nullptr,
            wbf_hi + oUV + (size_t)i*32768, wbf_lo + oUV + (size_t)i*32768,
            nullptr, uv_buf, vv_buf, nullptr, nullptr,
            128, F, F, F, 0);
        // h = silu([s|norm(vv)]@W1+b1) with stack fused into staging (252 blocks)
        gemm64<2, 1, 32><<<dim3(1, NP/32), dim3(256), 0, stream>>>(
            s_buf, nullptr, nullptr, vv_buf,
            wbf_hi + oU1 + (size_t)i*32768, wbf_lo + oU1 + (size_t)i*32768,
            upd_b1 + (size_t)i*F, nullptr, nullptr, hhi, hlo,
            256, 0, F, 0, 1);
        // a = h@W2+b2 -> phi_buf (378 blocks)
        gemm64<1, 0, 64><<<dim3(3, NP/64), dim3(256), 0, stream>>>(
            nullptr, hhi, hlo, nullptr,
            wbf_hi + oU2 + (size_t)i*49152, wbf_lo + oU2 + (size_t)i*49152,
            upd_b2 + (size_t)i*3*F, phi_buf, phi_buf, nullptr, nullptr,
            128, 3*F, 3*F, 3*F, 0);
        finupd_kernel<<<dim3(N_ATOMS * F / 256), dim3(256), 0, stream>>>(
            uv_buf, vv_buf, phi_buf, s_buf, vout);
        float* tmp = vin; vin = vout; vout = tmp;
    }

    readout_fused<<<dim3(N_ATOMS / 32), dim3(256), 0, stream>>>(
        s_buf, ro_w1, ro_b1, ro_w2, ro_b2, molidx, out);
}

// Round 8
// 443.834 us; speedup vs baseline: 1.5543x; 1.0446x over previous
//
#include <hip/hip_runtime.h>

static constexpr int F = 128;
static constexpr int N_RBF = 20;
static constexpr int N_ATOMS = 8000;
static constexpr int NP = 8064;          // padded to 128 (pad rows hold harness poison = tiny normal floats, benign)
static constexpr int N_EDGES = 160000;
static constexpr int N_MOLS = 100;
static constexpr float CUTOFF = 5.0f;
static constexpr size_t NFC = (size_t)NP * F;   // padded plane-equivalent size (buffer sizing)
static constexpr int REC = 28;           // packed edge record: j, ev, ux,uy,uz, rbf[20], pad[3]
#define PIF 3.14159265358979323846f

typedef __attribute__((ext_vector_type(8))) short bf16x8;
typedef __attribute__((ext_vector_type(4))) float f32x4;
typedef unsigned short ushort_t;
typedef unsigned int uint_t;

__device__ __forceinline__ float silu_f(float x) { return x / (1.f + __expf(-x)); }

__device__ __forceinline__ ushort_t f2bf(float x) {   // round-to-nearest-even
    union { float f; uint_t u; } v; v.f = x;
    uint_t r = v.u + 0x7fffu + ((v.u >> 16) & 1u);
    return (ushort_t)(r >> 16);
}
__device__ __forceinline__ float bf2f(ushort_t h) {
    union { uint_t u; float f; } v; v.u = ((uint_t)h) << 16; return v.f;
}

// ---------------- edge geometry + live-edge histogram ----------------
__global__ __launch_bounds__(256) void geom_kernel(
    const float* __restrict__ xyz, const int* __restrict__ nbrs,
    float* __restrict__ rbfe, float* __restrict__ envb, float* __restrict__ unitb,
    int* __restrict__ cnt)
{
    int e = blockIdx.x * 256 + threadIdx.x;
    if (e >= N_EDGES) return;
    int i0 = nbrs[2*e+0], i1 = nbrs[2*e+1];
    float dx = xyz[3*i1+0] - xyz[3*i0+0];
    float dy = xyz[3*i1+1] - xyz[3*i0+1];
    float dz = xyz[3*i1+2] - xyz[3*i0+2];
    float d  = sqrtf(dx*dx + dy*dy + dz*dz);
    float inv = 1.f / d;
    unitb[3*e+0] = dx*inv; unitb[3*e+1] = dy*inv; unitb[3*e+2] = dz*inv;
    float ev = (d <= CUTOFF) ? 0.5f*(cosf(PIF*d/CUTOFF) + 1.f) : 0.f;
    envb[e] = ev;
    float base = PIF*d/CUTOFF;
    float sc = inv * ev;   // fold env into rbf (w_s = (rbf*env)@W + b*env)
    #pragma unroll
    for (int k = 0; k < N_RBF; ++k)
        rbfe[e*N_RBF + k] = sinf((float)(k+1)*base) * sc;
    if (ev > 0.f) atomicAdd(&cnt[i0], 1);
}

// ---------------- exclusive scan of 8000 counters (single block) ----------------
__global__ __launch_bounds__(1024) void scan_kernel(
    const int* __restrict__ cnt, int* __restrict__ offsets)
{
    __shared__ int sums[1024];
    int tid = threadIdx.x;
    int base = tid * 8;
    int local[8]; int s = 0;
    #pragma unroll
    for (int i = 0; i < 8; ++i) {
        int idx = base + i;
        local[i] = (idx < N_ATOMS) ? cnt[idx] : 0;
        s += local[i];
    }
    sums[tid] = s;
    __syncthreads();
    for (int d = 1; d < 1024; d <<= 1) {
        int v = (tid >= d) ? sums[tid - d] : 0;
        __syncthreads();
        sums[tid] += v;
        __syncthreads();
    }
    int ex = (tid == 0) ? 0 : sums[tid - 1];
    #pragma unroll
    for (int i = 0; i < 8; ++i) {
        int idx = base + i;
        if (idx < N_ATOMS) { offsets[idx] = ex; ex += local[i]; }
    }
}

// ---------------- scatter: build packed records for live edges (sorted by target) ----------------
__global__ __launch_bounds__(256) void scatter_kernel(
    const int* __restrict__ nbrs, const float* __restrict__ envb,
    const float* __restrict__ rbfe, const float* __restrict__ unitb,
    const int* __restrict__ offsets, int* __restrict__ cursor,
    float* __restrict__ rec)
{
    int e = blockIdx.x * 256 + threadIdx.x;
    if (e >= N_EDGES) return;
    float ev = envb[e];
    if (ev <= 0.f) return;
    int tgt = nbrs[2*e+0];
    int pos = offsets[tgt] + atomicAdd(&cursor[tgt], 1);
    float* r = rec + (size_t)pos * REC;
    r[0] = __int_as_float(nbrs[2*e+1]);
    r[1] = ev;
    r[2] = unitb[3*e+0]; r[3] = unitb[3*e+1]; r[4] = unitb[3*e+2];
    #pragma unroll
    for (int k = 0; k < N_RBF; ++k) r[5 + k] = rbfe[e*N_RBF + k];
}

// ---------------- s = emb_table[z] ----------------
__global__ __launch_bounds__(256) void embed_kernel(
    const float* __restrict__ emb, const int* __restrict__ z, float* __restrict__ s)
{
    int idx = blockIdx.x * 256 + threadIdx.x;   // grid sized exactly N_ATOMS*F
    int n = idx >> 7, f = idx & 127;
    s[idx] = emb[z[n]*F + f];
}

// ---------------- weight prep: transpose + f32 -> (bf16 hi, bf16 lo) ----------------
// dst layout (bf16, [n][k] row-major K-contig), same offsets for hi and lo buffers:
//   W1t  3x(128n x 128k) @ 0        src msg_w1 (128k x 128n)
//   W2t  3x(384n x 128k) @ 49152    src msg_w2
//   UVt  3x(256n x 128k) @ 196608   src upd_u (n 0..127) | upd_v (n 128..255)
//   U1t  3x(128n x 256k) @ 294912   src upd_w1 (256k x 128n)
//   U2t  3x(384n x 128k) @ 393216   src upd_w2
//   ROt  128n x 128k    @ 540672    src ro_w1 (128k x 64n), cols 64..127 zero
//   robias[128] (f32)   idx 557056..557183: ro_b1 padded with zeros
static constexpr int WPREP_W = 557056;
static constexpr int WPREP_TOTAL = 557184;
__global__ __launch_bounds__(256) void wprep_kernel(
    const float* __restrict__ msg_w1, const float* __restrict__ msg_w2,
    const float* __restrict__ upd_u,  const float* __restrict__ upd_v,
    const float* __restrict__ upd_w1, const float* __restrict__ upd_w2,
    const float* __restrict__ ro_w1,  const float* __restrict__ ro_b1,
    ushort_t* __restrict__ dhi, ushort_t* __restrict__ dlo,
    float* __restrict__ robias)
{
    int idx = blockIdx.x * 256 + threadIdx.x;
    if (idx >= WPREP_TOTAL) return;
    if (idx >= WPREP_W) {
        int l = idx - WPREP_W;
        robias[l] = (l < 64) ? ro_b1[l] : 0.f;
        return;
    }
    float val;
    if (idx < 540672) {
        const float* src; int K, N, rem;
        if (idx < 49152)       { int l = idx;          int c = l / 16384; rem = l % 16384; K = 128; N = 128; src = msg_w1 + c * 16384; }
        else if (idx < 196608) { int l = idx - 49152;  int c = l / 49152; rem = l % 49152; K = 128; N = 384; src = msg_w2 + c * 49152; }
        else if (idx < 294912) { int l = idx - 196608; int c = l / 32768; rem = l % 32768; K = 128; N = 128;
                                 if (rem < 16384) src = upd_u + c * 16384;
                                 else { src = upd_v + c * 16384; rem -= 16384; } }
        else if (idx < 393216) { int l = idx - 294912; int c = l / 32768; rem = l % 32768; K = 256; N = 128; src = upd_w1 + c * 32768; }
        else                   { int l = idx - 393216; int c = l / 49152; rem = l % 49152; K = 128; N = 384; src = upd_w2 + c * 49152; }
        int n = rem / K, k = rem % K;
        val = src[k * N + n];
    } else {
        int l = idx - 540672;             // ro_w1 pad: [n][k], n>=64 -> 0
        int n = l >> 7, k = l & 127;
        val = (n < 64) ? ro_w1[k * 64 + n] : 0.f;
    }
    ushort_t h = f2bf(val);
    dhi[idx] = h;
    dlo[idx] = f2bf(val - bf2f(h));
}

// ---------------- MFMA bf16x3 GEMM, TM x 128 tile ----------------
// f32 accuracy: A@B ~= Ah@Bh + Ah@Bl + Al@Bh (drop lo*lo, ~2^-18 rel).
// AMODE 0: A f32 MxK.  AMODE 1: A pre-split hi/lo bf16 (K-contig).
// AMODE 2: virtual A = [s | norm(vv)] (K=256; k<128 from s f32, k>=128 = ||vv|| on the fly;
//          vv layout [n][3][f]).
// OUTMODE 0: f32, split-column (C0/C1).  OUTMODE 1: bf16 hi/lo (Chi/Clo, ld0).
// Bt hi/lo: Nc x K bf16 K-contig. 256 threads = 4 waves, each wave 32 N-cols.
template<int AMODE, int OUTMODE, int TM>
__global__ __launch_bounds__(256) void gemm64(
    const float* __restrict__ Af, const ushort_t* __restrict__ Ahi,
    const ushort_t* __restrict__ Alo, const float* __restrict__ vvp,
    const ushort_t* __restrict__ Bhi, const ushort_t* __restrict__ Blo,
    const float* __restrict__ bias,
    float* __restrict__ C0, float* __restrict__ C1,
    ushort_t* __restrict__ Chi, ushort_t* __restrict__ Clo,
    int K, int split, int ld0, int ld1, int act)
{
    constexpr int MI = TM / 16;            // m fragment tiles
    constexpr int EA = TM * 32 / 256;      // A elems per thread per k-iter (8 or 4)
    __shared__ __align__(16) ushort_t Ah[TM * 40];
    __shared__ __align__(16) ushort_t Al[TM * 40];
    __shared__ __align__(16) ushort_t Bh[128 * 40];
    __shared__ __align__(16) ushort_t Bl[128 * 40];
    const int tid = threadIdx.x;
    const int wave = tid >> 6, lane = tid & 63;
    const int row_l = lane & 15, quad = lane >> 4;
    const int wn = wave * 32;
    const int m0 = blockIdx.y * TM, n0 = blockIdx.x * 128;
    const int lrA = tid / (32 / EA);
    const int ksA = (tid % (32 / EA)) * EA;
    const int lrB = tid >> 1, ksB = (tid & 1) * 16;

    f32x4 acc[MI][2];
    #pragma unroll
    for (int i = 0; i < MI; ++i)
        #pragma unroll
        for (int j = 0; j < 2; ++j)
            #pragma unroll
            for (int r = 0; r < 4; ++r) acc[i][j][r] = 0.f;

    for (int k0 = 0; k0 < K; k0 += 32) {
        // ---- stage A ----
        if constexpr (AMODE == 1) {
            const ushort_t* ah = &Ahi[(size_t)(m0 + lrA) * K + k0 + ksA];
            const ushort_t* al = &Alo[(size_t)(m0 + lrA) * K + k0 + ksA];
            if constexpr (EA == 8) {
                *(uint4*)&Ah[lrA * 40 + ksA] = *(const uint4*)ah;
                *(uint4*)&Al[lrA * 40 + ksA] = *(const uint4*)al;
            } else {
                *(uint2*)&Ah[lrA * 40 + ksA] = *(const uint2*)ah;
                *(uint2*)&Al[lrA * 40 + ksA] = *(const uint2*)al;
            }
        } else {
            float e[EA];
            if constexpr (AMODE == 0) {
                const float* ap = &Af[(size_t)(m0 + lrA) * K + k0 + ksA];
                #pragma unroll
                for (int q = 0; q < EA / 4; ++q) {
                    float4 v = *(const float4*)(ap + q * 4);
                    e[q*4+0] = v.x; e[q*4+1] = v.y; e[q*4+2] = v.z; e[q*4+3] = v.w;
                }
            } else {   // AMODE 2
                if (k0 + ksA < 128) {
                    const float* ap = &Af[(size_t)(m0 + lrA) * 128 + k0 + ksA];
                    #pragma unroll
                    for (int q = 0; q < EA / 4; ++q) {
                        float4 v = *(const float4*)(ap + q * 4);
                        e[q*4+0] = v.x; e[q*4+1] = v.y; e[q*4+2] = v.z; e[q*4+3] = v.w;
                    }
                } else {
                    int f = k0 + ksA - 128;
                    const float* px = &vvp[((size_t)(m0 + lrA) * 3) * F + f];   // [n][3][f]
                    #pragma unroll
                    for (int q = 0; q < EA / 4; ++q) {
                        float4 x = *(const float4*)(px + q * 4);
                        float4 y = *(const float4*)(px + F + q * 4);
                        float4 z = *(const float4*)(px + 2 * F + q * 4);
                        e[q*4+0] = sqrtf(x.x*x.x + y.x*y.x + z.x*z.x + 1e-15f);
                        e[q*4+1] = sqrtf(x.y*x.y + y.y*y.y + z.y*z.y + 1e-15f);
                        e[q*4+2] = sqrtf(x.z*x.z + y.z*y.z + z.z*z.z + 1e-15f);
                        e[q*4+3] = sqrtf(x.w*x.w + y.w*y.w + z.w*z.w + 1e-15f);
                    }
                }
            }
            ushort_t ph[EA], pl[EA];
            #pragma unroll
            for (int t = 0; t < EA; ++t) {
                ushort_t h = f2bf(e[t]);
                ph[t] = h; pl[t] = f2bf(e[t] - bf2f(h));
            }
            if constexpr (EA == 8) {
                *(uint4*)&Ah[lrA * 40 + ksA] = *(uint4*)ph;
                *(uint4*)&Al[lrA * 40 + ksA] = *(uint4*)pl;
            } else {
                *(uint2*)&Ah[lrA * 40 + ksA] = *(uint2*)ph;
                *(uint2*)&Al[lrA * 40 + ksA] = *(uint2*)pl;
            }
        }
        // ---- stage B (always pre-split bf16) ----
        {
            const ushort_t* bh = &Bhi[(size_t)(n0 + lrB) * K + k0 + ksB];
            const ushort_t* bl = &Blo[(size_t)(n0 + lrB) * K + k0 + ksB];
            *(uint4*)&Bh[lrB * 40 + ksB]     = *(const uint4*)bh;
            *(uint4*)&Bh[lrB * 40 + ksB + 8] = *(const uint4*)(bh + 8);
            *(uint4*)&Bl[lrB * 40 + ksB]     = *(const uint4*)bl;
            *(uint4*)&Bl[lrB * 40 + ksB + 8] = *(const uint4*)(bl + 8);
        }
        __syncthreads();
        bf16x8 ahf[MI], alf[MI], bhf[2], blf[2];
        #pragma unroll
        for (int i = 0; i < MI; ++i) {
            int ar = (i * 16 + row_l) * 40 + quad * 8;
            ahf[i] = *(const bf16x8*)&Ah[ar];
            alf[i] = *(const bf16x8*)&Al[ar];
        }
        #pragma unroll
        for (int j = 0; j < 2; ++j) {
            int br = (wn + j * 16 + row_l) * 40 + quad * 8;
            bhf[j] = *(const bf16x8*)&Bh[br];
            blf[j] = *(const bf16x8*)&Bl[br];
        }
        #pragma unroll
        for (int i = 0; i < MI; ++i)
            #pragma unroll
            for (int j = 0; j < 2; ++j) {
                acc[i][j] = __builtin_amdgcn_mfma_f32_16x16x32_bf16(ahf[i], bhf[j], acc[i][j], 0, 0, 0);
                acc[i][j] = __builtin_amdgcn_mfma_f32_16x16x32_bf16(ahf[i], blf[j], acc[i][j], 0, 0, 0);
                acc[i][j] = __builtin_amdgcn_mfma_f32_16x16x32_bf16(alf[i], bhf[j], acc[i][j], 0, 0, 0);
            }
        __syncthreads();
    }

    // ---- epilogue: D[row][col]: col = lane&15 (+tiles), row = quad*4 + r (+tiles) ----
    #pragma unroll
    for (int j = 0; j < 2; ++j) {
        int col = n0 + wn + j * 16 + row_l;
        float bval = bias ? bias[col] : 0.f;
        if constexpr (OUTMODE == 0) {
            float* Cp; int ccol, ld;
            if (col < split) { Cp = C0; ccol = col; ld = ld0; }
            else             { Cp = C1; ccol = col - split; ld = ld1; }
            #pragma unroll
            for (int i = 0; i < MI; ++i)
                #pragma unroll
                for (int r = 0; r < 4; ++r) {
                    int row = m0 + i * 16 + quad * 4 + r;
                    float v = acc[i][j][r] + bval;
                    if (act) v = silu_f(v);
                    Cp[(size_t)row * ld + ccol] = v;
                }
        } else {
            #pragma unroll
            for (int i = 0; i < MI; ++i)
                #pragma unroll
                for (int r = 0; r < 4; ++r) {
                    int row = m0 + i * 16 + quad * 4 + r;
                    float v = acc[i][j][r] + bval;
                    if (act) v = silu_f(v);
                    ushort_t h = f2bf(v);
                    Chi[(size_t)row * ld0 + col] = h;
                    Clo[(size_t)row * ld0 + col] = f2bf(v - bf2f(h));
                }
        }
    }
}

// ---------------- atom-centric message gather (atomic-free, packed records) ----------------
// v layout: [n][3][f]. ZVIN=1: v_in is implicitly zero (conv 0) — skip reads.
template<int ZVIN>
__global__ __launch_bounds__(128) void msg_gather(
    const float* __restrict__ phi, const float* __restrict__ rec,
    const float* __restrict__ rbf_w, const float* __restrict__ rbf_b,
    const float* __restrict__ v_in, float* __restrict__ s,
    float* __restrict__ v_out, const int* __restrict__ offsets,
    const int* __restrict__ cnt)
{
    const int n = blockIdx.x, tid = threadIdx.x;
    float W0[N_RBF], W1[N_RBF], W2[N_RBF];
    #pragma unroll
    for (int k = 0; k < N_RBF; ++k) {
        W0[k] = rbf_w[k*3*F + tid];
        W1[k] = rbf_w[k*3*F + F + tid];
        W2[k] = rbf_w[k*3*F + 2*F + tid];
    }
    const float b0 = rbf_b[tid], b1 = rbf_b[F + tid], b2 = rbf_b[2*F + tid];
    float ds = 0.f, dvx = 0.f, dvy = 0.f, dvz = 0.f;
    const int off = offsets[n], c = cnt[n];
    const float* r = rec + (size_t)off * REC;
    #pragma unroll 2
    for (int t = 0; t < c; ++t, r += REC) {
        int j = __float_as_int(r[0]);
        float ev = r[1];
        float ux = r[2], uy = r[3], uz = r[4];
        float w0 = b0 * ev, w1 = b1 * ev, w2 = b2 * ev;
        #pragma unroll
        for (int k = 0; k < N_RBF; ++k) {
            float rk = r[5 + k];
            w0 += rk * W0[k]; w1 += rk * W1[k]; w2 += rk * W2[k];
        }
        const float* prow = phi + (size_t)j * 3 * F;
        float s0 = prow[tid] * w0;
        float s1 = prow[F + tid] * w1;
        float s2 = prow[2*F + tid] * w2;
        ds  += s1;
        if constexpr (ZVIN) {
            dvx += s2*ux; dvy += s2*uy; dvz += s2*uz;
        } else {
            const float* vrow = v_in + (size_t)j * 3 * F;
            dvx += s2*ux + s0 * vrow[tid];
            dvy += s2*uy + s0 * vrow[F + tid];
            dvz += s2*uz + s0 * vrow[2*F + tid];
        }
    }
    s[(size_t)n * F + tid] += ds;
    size_t vb = (size_t)n * 3 * F + tid;
    if constexpr (ZVIN) {
        v_out[vb]       = dvx;
        v_out[vb + F]   = dvy;
        v_out[vb + 2*F] = dvz;
    } else {
        v_out[vb]       = v_in[vb]       + dvx;
        v_out[vb + F]   = v_in[vb + F]   + dvy;
        v_out[vb + 2*F] = v_in[vb + 2*F] + dvz;
    }
}

// ---------------- final conv update (v layout [n][3][f]) ----------------
__global__ __launch_bounds__(256) void finupd_kernel(
    const float* __restrict__ uv, const float* __restrict__ vv,
    const float* __restrict__ a, float* __restrict__ s, float* __restrict__ v)
{
    size_t idx = (size_t)blockIdx.x * 256 + threadIdx.x;   // < N_ATOMS*F
    int n = (int)(idx >> 7), f = (int)(idx & 127);
    size_t vb = (size_t)n * 3 * F + f;
    float ux = uv[vb], uy = uv[vb + F], uz = uv[vb + 2*F];
    float wx = vv[vb], wy = vv[vb + F], wz = vv[vb + 2*F];
    float dot = ux*wx + uy*wy + uz*wz;
    const float* arow = a + (size_t)n * 3 * F;
    s[idx] += dot * arow[F + f] + arow[2*F + f];
    float avv = arow[f];
    v[vb]        += ux * avv;
    v[vb + F]    += uy * avv;
    v[vb + 2*F]  += uz * avv;
}

// ---------------- readout reduce: atom_e = h2[n][0:64]·w2 + b2; LDS mol table ----------------
// 32 blocks x 250 sorted atoms. ~5 global atomics per block instead of 250.
__global__ __launch_bounds__(256) void rreduce_kernel(
    const float* __restrict__ h2, const float* __restrict__ w2,
    const float* __restrict__ b2, const int* __restrict__ mol,
    float* __restrict__ out)
{
    __shared__ float molacc[128];
    int tid = threadIdx.x, wave = tid >> 6, lane = tid & 63;
    if (tid < 128) molacc[tid] = 0.f;
    float w2v = w2[lane], b2v = b2[0];
    int n0 = blockIdx.x * 250;
    __syncthreads();
    for (int t = wave; t < 250; t += 4) {
        int n = n0 + t;
        float val = h2[(size_t)n * 128 + lane] * w2v;
        #pragma unroll
        for (int o = 32; o > 0; o >>= 1) val += __shfl_down(val, o);
        if (lane == 0) atomicAdd(&molacc[mol[n]], val + b2v);
    }
    __syncthreads();
    int lo = mol[n0], hi = mol[n0 + 249];
    for (int m = lo + tid; m <= hi; m += 256)
        atomicAdd(&out[m], molacc[m]);
}

extern "C" void kernel_launch(void* const* d_in, const int* in_sizes, int n_in,
                              void* d_out, int out_size, void* d_ws, size_t ws_size,
                              hipStream_t stream)
{
    const float* xyz    = (const float*)d_in[0];
    const float* emb    = (const float*)d_in[1];
    const float* msg_w1 = (const float*)d_in[2];
    const float* msg_b1 = (const float*)d_in[3];
    const float* msg_w2 = (const float*)d_in[4];
    const float* msg_b2 = (const float*)d_in[5];
    const float* rbf_w  = (const float*)d_in[6];
    const float* rbf_b  = (const float*)d_in[7];
    const float* upd_u  = (const float*)d_in[8];
    const float* upd_v  = (const float*)d_in[9];
    const float* upd_w1 = (const float*)d_in[10];
    const float* upd_b1 = (const float*)d_in[11];
    const float* upd_w2 = (const float*)d_in[12];
    const float* upd_b2 = (const float*)d_in[13];
    const float* ro_w1  = (const float*)d_in[14];
    const float* ro_b1  = (const float*)d_in[15];
    const float* ro_w2  = (const float*)d_in[16];
    const float* ro_b2  = (const float*)d_in[17];
    const int*   z      = (const int*)d_in[18];
    const int*   nbrs   = (const int*)d_in[19];
    const int*   molidx = (const int*)d_in[20];
    float* out = (float*)d_out;

    float* ws = (float*)d_ws;
    size_t off = 0;
    auto alloc = [&](size_t n) { float* p = ws + off; off += n; return p; };
    float* s_buf   = alloc(NFC);
    float* v1_buf  = alloc(3 * NFC);       // [n][3][f]
    float* v2_buf  = alloc(3 * NFC);
    float* uv_buf  = alloc(3 * NFC);
    float* vv_buf  = alloc(3 * NFC);
    float* phi_buf = alloc(3 * NFC);       // phi / a / readout-hidden
    ushort_t* hhi  = (ushort_t*)alloc(NFC / 2);   // hidden activations, bf16 hi/lo
    ushort_t* hlo  = (ushort_t*)alloc(NFC / 2);
    float* rbfe    = alloc((size_t)N_EDGES * N_RBF);
    float* envb    = alloc(N_EDGES);
    float* unitb   = alloc((size_t)N_EDGES * 3);
    float* edgerec = alloc((size_t)N_EDGES * REC);
    ushort_t* wbf_hi = (ushort_t*)alloc(WPREP_W / 2 + 64);
    ushort_t* wbf_lo = (ushort_t*)alloc(WPREP_W / 2 + 64);
    float* robias   = alloc(128);
    int* cnt        = (int*)alloc(N_ATOMS);
    int* cursor     = (int*)alloc(N_ATOMS);
    int* offsets    = (int*)alloc(N_ATOMS);

    // bf16 weight sub-offsets (elements, see wprep_kernel)
    const size_t oW1 = 0, oW2 = 49152, oUV = 196608, oU1 = 294912, oU2 = 393216, oRO = 540672;

    hipMemsetAsync(out, 0, sizeof(float) * N_MOLS, stream);
    hipMemsetAsync(cnt, 0, sizeof(int) * 2 * N_ATOMS, stream);   // cnt + cursor adjacent

    geom_kernel<<<dim3((N_EDGES + 255) / 256), dim3(256), 0, stream>>>(
        xyz, nbrs, rbfe, envb, unitb, cnt);
    scan_kernel<<<dim3(1), dim3(1024), 0, stream>>>(cnt, offsets);
    scatter_kernel<<<dim3((N_EDGES + 255) / 256), dim3(256), 0, stream>>>(
        nbrs, envb, rbfe, unitb, offsets, cursor, edgerec);
    embed_kernel<<<dim3(N_ATOMS * F / 256), dim3(256), 0, stream>>>(emb, z, s_buf);
    wprep_kernel<<<dim3((WPREP_TOTAL + 255) / 256), dim3(256), 0, stream>>>(
        msg_w1, msg_w2, upd_u, upd_v, upd_w1, upd_w2, ro_w1, ro_b1,
        wbf_hi, wbf_lo, robias);

    float* vin = v1_buf;
    float* vout = v2_buf;
    for (int i = 0; i < 3; ++i) {
        // h = silu(s@W1+b1) -> bf16 hi/lo  (TM=32: 252 blocks)
        gemm64<0, 1, 32><<<dim3(1, NP/32), dim3(256), 0, stream>>>(
            s_buf, nullptr, nullptr, nullptr,
            wbf_hi + oW1 + (size_t)i*16384, wbf_lo + oW1 + (size_t)i*16384,
            msg_b1 + (size_t)i*F, nullptr, nullptr, hhi, hlo,
            128, 0, F, 0, 1);
        // phi = h@W2+b2  (378 blocks)
        gemm64<1, 0, 64><<<dim3(3, NP/64), dim3(256), 0, stream>>>(
            nullptr, hhi, hlo, nullptr,
            wbf_hi + oW2 + (size_t)i*49152, wbf_lo + oW2 + (size_t)i*49152,
            msg_b2 + (size_t)i*3*F, phi_buf, phi_buf, nullptr, nullptr,
            128, 3*F, 3*F, 3*F, 0);
        // atomic-free message gather: s += ds in place; vout = vin + dv
        if (i == 0)
            msg_gather<1><<<dim3(N_ATOMS), dim3(128), 0, stream>>>(
                phi_buf, edgerec, rbf_w + (size_t)i*N_RBF*3*F, rbf_b + (size_t)i*3*F,
                vin, s_buf, vout, offsets, cnt);
        else
            msg_gather<0><<<dim3(N_ATOMS), dim3(128), 0, stream>>>(
                phi_buf, edgerec, rbf_w + (size_t)i*N_RBF*3*F, rbf_b + (size_t)i*3*F,
                vin, s_buf, vout, offsets, cnt);
        // fused u_v|v_v: one GEMM over M=3*NP rows ([n][3] row order), split-column (756 blocks)
        gemm64<0, 0, 64><<<dim3(2, 3*NP/64), dim3(256), 0, stream>>>(
            vout, nullptr, nullptr, nullptr,
            wbf_hi + oUV + (size_t)i*32768, wbf_lo + oUV + (size_t)i*32768,
            nullptr, uv_buf, vv_buf, nullptr, nullptr,
            128, F, F, F, 0);
        // h = silu([s|norm(vv)]@W1+b1) with stack fused into staging (252 blocks)
        gemm64<2, 1, 32><<<dim3(1, NP/32), dim3(256), 0, stream>>>(
            s_buf, nullptr, nullptr, vv_buf,
            wbf_hi + oU1 + (size_t)i*32768, wbf_lo + oU1 + (size_t)i*32768,
            upd_b1 + (size_t)i*F, nullptr, nullptr, hhi, hlo,
            256, 0, F, 0, 1);
        // a = h@W2+b2 -> phi_buf (378 blocks)
        gemm64<1, 0, 64><<<dim3(3, NP/64), dim3(256), 0, stream>>>(
            nullptr, hhi, hlo, nullptr,
            wbf_hi + oU2 + (size_t)i*49152, wbf_lo + oU2 + (size_t)i*49152,
            upd_b2 + (size_t)i*3*F, phi_buf, phi_buf, nullptr, nullptr,
            128, 3*F, 3*F, 3*F, 0);
        finupd_kernel<<<dim3(N_ATOMS * F / 256), dim3(256), 0, stream>>>(
            uv_buf, vv_buf, phi_buf, s_buf, vout);
        float* tmp = vin; vin = vout; vout = tmp;
    }

    // readout: h2 = silu(s @ ro_w1pad + b1pad) via MFMA (252 blocks), then LDS-table reduce
    gemm64<0, 0, 32><<<dim3(1, NP/32), dim3(256), 0, stream>>>(
        s_buf, nullptr, nullptr, nullptr,
        wbf_hi + oRO, wbf_lo + oRO,
        robias, phi_buf, phi_buf, nullptr, nullptr,
        128, 128, 128, 128, 1);
    rreduce_kernel<<<dim3(32), dim3(256), 0, stream>>>(
        phi_buf, ro_w2, ro_b2, molidx, out);
}

// Round 10
// 422.566 us; speedup vs baseline: 1.6325x; 1.0503x over previous
//
#include <hip/hip_runtime.h>

static constexpr int F = 128;
static constexpr int N_RBF = 20;
static constexpr int N_ATOMS = 8000;
static constexpr int NP = 8064;          // padded to 128 (pad rows hold harness poison = tiny normal floats, benign)
static constexpr int N_EDGES = 160000;
static constexpr int N_MOLS = 100;
static constexpr float CUTOFF = 5.0f;
static constexpr size_t NFC = (size_t)NP * F;   // padded plane-equivalent size (buffer sizing)
static constexpr int REC = 28;           // packed edge record: j, ev, ux,uy,uz, rbf[20], pad[3]
#define PIF 3.14159265358979323846f

typedef __attribute__((ext_vector_type(8))) short bf16x8;
typedef __attribute__((ext_vector_type(4))) float f32x4;
typedef unsigned short ushort_t;
typedef unsigned int uint_t;

__device__ __forceinline__ float silu_f(float x) { return x / (1.f + __expf(-x)); }

__device__ __forceinline__ ushort_t f2bf(float x) {   // round-to-nearest-even
    union { float f; uint_t u; } v; v.f = x;
    uint_t r = v.u + 0x7fffu + ((v.u >> 16) & 1u);
    return (ushort_t)(r >> 16);
}
__device__ __forceinline__ float bf2f(ushort_t h) {
    union { uint_t u; float f; } v; v.u = ((uint_t)h) << 16; return v.f;
}

// ---------------- edge geometry + live-edge histogram ----------------
__global__ __launch_bounds__(256) void geom_kernel(
    const float* __restrict__ xyz, const int* __restrict__ nbrs,
    float* __restrict__ rbfe, float* __restrict__ envb, float* __restrict__ unitb,
    int* __restrict__ cnt)
{
    int e = blockIdx.x * 256 + threadIdx.x;
    if (e >= N_EDGES) return;
    int i0 = nbrs[2*e+0], i1 = nbrs[2*e+1];
    float dx = xyz[3*i1+0] - xyz[3*i0+0];
    float dy = xyz[3*i1+1] - xyz[3*i0+1];
    float dz = xyz[3*i1+2] - xyz[3*i0+2];
    float d  = sqrtf(dx*dx + dy*dy + dz*dz);
    float inv = 1.f / d;
    unitb[3*e+0] = dx*inv; unitb[3*e+1] = dy*inv; unitb[3*e+2] = dz*inv;
    float ev = (d <= CUTOFF) ? 0.5f*(cosf(PIF*d/CUTOFF) + 1.f) : 0.f;
    envb[e] = ev;
    float base = PIF*d/CUTOFF;
    float sc = inv * ev;   // fold env into rbf (w_s = (rbf*env)@W + b*env)
    #pragma unroll
    for (int k = 0; k < N_RBF; ++k)
        rbfe[e*N_RBF + k] = sinf((float)(k+1)*base) * sc;
    if (ev > 0.f) atomicAdd(&cnt[i0], 1);
}

// ---------------- exclusive scan of 8000 counters (single block) ----------------
__global__ __launch_bounds__(1024) void scan_kernel(
    const int* __restrict__ cnt, int* __restrict__ offsets)
{
    __shared__ int sums[1024];
    int tid = threadIdx.x;
    int base = tid * 8;
    int local[8]; int s = 0;
    #pragma unroll
    for (int i = 0; i < 8; ++i) {
        int idx = base + i;
        local[i] = (idx < N_ATOMS) ? cnt[idx] : 0;
        s += local[i];
    }
    sums[tid] = s;
    __syncthreads();
    for (int d = 1; d < 1024; d <<= 1) {
        int v = (tid >= d) ? sums[tid - d] : 0;
        __syncthreads();
        sums[tid] += v;
        __syncthreads();
    }
    int ex = (tid == 0) ? 0 : sums[tid - 1];
    #pragma unroll
    for (int i = 0; i < 8; ++i) {
        int idx = base + i;
        if (idx < N_ATOMS) { offsets[idx] = ex; ex += local[i]; }
    }
}

// ---------------- scatter: build packed records for live edges (sorted by target) ----------------
__global__ __launch_bounds__(256) void scatter_kernel(
    const int* __restrict__ nbrs, const float* __restrict__ envb,
    const float* __restrict__ rbfe, const float* __restrict__ unitb,
    const int* __restrict__ offsets, int* __restrict__ cursor,
    float* __restrict__ rec)
{
    int e = blockIdx.x * 256 + threadIdx.x;
    if (e >= N_EDGES) return;
    float ev = envb[e];
    if (ev <= 0.f) return;
    int tgt = nbrs[2*e+0];
    int pos = offsets[tgt] + atomicAdd(&cursor[tgt], 1);
    float* r = rec + (size_t)pos * REC;
    r[0] = __int_as_float(nbrs[2*e+1]);
    r[1] = ev;
    r[2] = unitb[3*e+0]; r[3] = unitb[3*e+1]; r[4] = unitb[3*e+2];
    #pragma unroll
    for (int k = 0; k < N_RBF; ++k) r[5 + k] = rbfe[e*N_RBF + k];
}

// ---------------- s = emb_table[z] ----------------
__global__ __launch_bounds__(256) void embed_kernel(
    const float* __restrict__ emb, const int* __restrict__ z, float* __restrict__ s)
{
    int idx = blockIdx.x * 256 + threadIdx.x;   // grid sized exactly N_ATOMS*F
    int n = idx >> 7, f = idx & 127;
    s[idx] = emb[z[n]*F + f];
}

// ---------------- weight prep: transpose + f32 -> (bf16 hi, bf16 lo) ----------------
// dst layout (bf16, [n][k] row-major K-contig), same offsets for hi and lo buffers:
//   W1t  3x(128n x 128k) @ 0        src msg_w1 (128k x 128n)
//   W2t  3x(384n x 128k) @ 49152    src msg_w2
//   UVt  3x(256n x 128k) @ 196608   src upd_u (n 0..127) | upd_v (n 128..255)
//   U1t  3x(128n x 256k) @ 294912   src upd_w1 (256k x 128n)
//   U2t  3x(384n x 128k) @ 393216   src upd_w2
//   ROt  128n x 128k    @ 540672    src ro_w1 (128k x 64n), cols 64..127 zero
//   robias[128] (f32)   idx 557056..557183: ro_b1 padded with zeros
static constexpr int WPREP_W = 557056;
static constexpr int WPREP_TOTAL = 557184;
__global__ __launch_bounds__(256) void wprep_kernel(
    const float* __restrict__ msg_w1, const float* __restrict__ msg_w2,
    const float* __restrict__ upd_u,  const float* __restrict__ upd_v,
    const float* __restrict__ upd_w1, const float* __restrict__ upd_w2,
    const float* __restrict__ ro_w1,  const float* __restrict__ ro_b1,
    ushort_t* __restrict__ dhi, ushort_t* __restrict__ dlo,
    float* __restrict__ robias)
{
    int idx = blockIdx.x * 256 + threadIdx.x;
    if (idx >= WPREP_TOTAL) return;
    if (idx >= WPREP_W) {
        int l = idx - WPREP_W;
        robias[l] = (l < 64) ? ro_b1[l] : 0.f;
        return;
    }
    float val;
    if (idx < 540672) {
        const float* src; int K, N, rem;
        if (idx < 49152)       { int l = idx;          int c = l / 16384; rem = l % 16384; K = 128; N = 128; src = msg_w1 + c * 16384; }
        else if (idx < 196608) { int l = idx - 49152;  int c = l / 49152; rem = l % 49152; K = 128; N = 384; src = msg_w2 + c * 49152; }
        else if (idx < 294912) { int l = idx - 196608; int c = l / 32768; rem = l % 32768; K = 128; N = 128;
                                 if (rem < 16384) src = upd_u + c * 16384;
                                 else { src = upd_v + c * 16384; rem -= 16384; } }
        else if (idx < 393216) { int l = idx - 294912; int c = l / 32768; rem = l % 32768; K = 256; N = 128; src = upd_w1 + c * 32768; }
        else                   { int l = idx - 393216; int c = l / 49152; rem = l % 49152; K = 128; N = 384; src = upd_w2 + c * 49152; }
        int n = rem / K, k = rem % K;
        val = src[k * N + n];
    } else {
        int l = idx - 540672;             // ro_w1 pad: [n][k], n>=64 -> 0
        int n = l >> 7, k = l & 127;
        val = (n < 64) ? ro_w1[k * 64 + n] : 0.f;
    }
    ushort_t h = f2bf(val);
    dhi[idx] = h;
    dlo[idx] = f2bf(val - bf2f(h));
}

// ---------------- MFMA bf16x3 GEMM, TM x 128 tile (used for UV + readout) ----------------
// A f32 MxK, Bt hi/lo Nc x K bf16 K-contig. 256 threads = 4 waves, each wave 32 N-cols.
// f32, split-column output (C0/C1).
template<int TM>
__global__ __launch_bounds__(256) void gemm64(
    const float* __restrict__ Af,
    const ushort_t* __restrict__ Bhi, const ushort_t* __restrict__ Blo,
    const float* __restrict__ bias,
    float* __restrict__ C0, float* __restrict__ C1,
    int K, int split, int ld0, int ld1, int act)
{
    constexpr int MI = TM / 16;            // m fragment tiles
    constexpr int EA = TM * 32 / 256;      // A elems per thread per k-iter (8 or 4)
    __shared__ __align__(16) ushort_t Ah[TM * 40];
    __shared__ __align__(16) ushort_t Al[TM * 40];
    __shared__ __align__(16) ushort_t Bh[128 * 40];
    __shared__ __align__(16) ushort_t Bl[128 * 40];
    const int tid = threadIdx.x;
    const int wave = tid >> 6, lane = tid & 63;
    const int row_l = lane & 15, quad = lane >> 4;
    const int wn = wave * 32;
    const int m0 = blockIdx.y * TM, n0 = blockIdx.x * 128;
    const int lrA = tid / (32 / EA);
    const int ksA = (tid % (32 / EA)) * EA;
    const int lrB = tid >> 1, ksB = (tid & 1) * 16;

    f32x4 acc[MI][2];
    #pragma unroll
    for (int i = 0; i < MI; ++i)
        #pragma unroll
        for (int j = 0; j < 2; ++j)
            #pragma unroll
            for (int r = 0; r < 4; ++r) acc[i][j][r] = 0.f;

    for (int k0 = 0; k0 < K; k0 += 32) {
        // ---- stage A (f32 -> hi/lo) ----
        {
            float e[EA];
            const float* ap = &Af[(size_t)(m0 + lrA) * K + k0 + ksA];
            #pragma unroll
            for (int q = 0; q < EA / 4; ++q) {
                float4 v = *(const float4*)(ap + q * 4);
                e[q*4+0] = v.x; e[q*4+1] = v.y; e[q*4+2] = v.z; e[q*4+3] = v.w;
            }
            ushort_t ph[EA], pl[EA];
            #pragma unroll
            for (int t = 0; t < EA; ++t) {
                ushort_t h = f2bf(e[t]);
                ph[t] = h; pl[t] = f2bf(e[t] - bf2f(h));
            }
            if constexpr (EA == 8) {
                *(uint4*)&Ah[lrA * 40 + ksA] = *(uint4*)ph;
                *(uint4*)&Al[lrA * 40 + ksA] = *(uint4*)pl;
            } else {
                *(uint2*)&Ah[lrA * 40 + ksA] = *(uint2*)ph;
                *(uint2*)&Al[lrA * 40 + ksA] = *(uint2*)pl;
            }
        }
        // ---- stage B (16 bf16 per thread per operand: ksB and ksB+8) ----
        {
            const ushort_t* bh = &Bhi[(size_t)(n0 + lrB) * K + k0 + ksB];
            const ushort_t* bl = &Blo[(size_t)(n0 + lrB) * K + k0 + ksB];
            *(uint4*)&Bh[lrB * 40 + ksB]     = *(const uint4*)bh;
            *(uint4*)&Bh[lrB * 40 + ksB + 8] = *(const uint4*)(bh + 8);
            *(uint4*)&Bl[lrB * 40 + ksB]     = *(const uint4*)bl;
            *(uint4*)&Bl[lrB * 40 + ksB + 8] = *(const uint4*)(bl + 8);
        }
        __syncthreads();
        bf16x8 ahf[MI], alf[MI], bhf[2], blf[2];
        #pragma unroll
        for (int i = 0; i < MI; ++i) {
            int ar = (i * 16 + row_l) * 40 + quad * 8;
            ahf[i] = *(const bf16x8*)&Ah[ar];
            alf[i] = *(const bf16x8*)&Al[ar];
        }
        #pragma unroll
        for (int j = 0; j < 2; ++j) {
            int br = (wn + j * 16 + row_l) * 40 + quad * 8;
            bhf[j] = *(const bf16x8*)&Bh[br];
            blf[j] = *(const bf16x8*)&Bl[br];
        }
        #pragma unroll
        for (int i = 0; i < MI; ++i)
            #pragma unroll
            for (int j = 0; j < 2; ++j) {
                acc[i][j] = __builtin_amdgcn_mfma_f32_16x16x32_bf16(ahf[i], bhf[j], acc[i][j], 0, 0, 0);
                acc[i][j] = __builtin_amdgcn_mfma_f32_16x16x32_bf16(ahf[i], blf[j], acc[i][j], 0, 0, 0);
                acc[i][j] = __builtin_amdgcn_mfma_f32_16x16x32_bf16(alf[i], bhf[j], acc[i][j], 0, 0, 0);
            }
        __syncthreads();
    }

    #pragma unroll
    for (int j = 0; j < 2; ++j) {
        int col = n0 + wn + j * 16 + row_l;
        float bval = bias ? bias[col] : 0.f;
        float* Cp; int ccol, ld;
        if (col < split) { Cp = C0; ccol = col; ld = ld0; }
        else             { Cp = C1; ccol = col - split; ld = ld1; }
        #pragma unroll
        for (int i = 0; i < MI; ++i)
            #pragma unroll
            for (int r = 0; r < 4; ++r) {
                int row = m0 + i * 16 + quad * 4 + r;
                float v = acc[i][j][r] + bval;
                if (act) v = silu_f(v);
                Cp[(size_t)row * ld + ccol] = v;
            }
    }
}

// ---------------- fused MLP: OUT = silu(A@W1+b1)@W2+b2 (bf16x3 MFMA, h stays in LDS) ----------------
// STACK 0: A = s (K1=128). STACK 1: A = [s | norm(vv)] (K1=256, vv layout [n][3][f]).
// FIN 0: write OUT (Nx384 f32) to C.  FIN 1: keep OUT ('a') in LDS; inline finupd for the
//        block's 32 atoms: s += <uv,vv>*a_sv + a_ss ; v += uv*a_vv.
// 32 rows/block, 256 threads = 4 waves.
template<int STACK, int FIN>
__global__ __launch_bounds__(256) void mlp2_kernel(
    const float* __restrict__ sbuf, const float* __restrict__ vvp,
    const ushort_t* __restrict__ W1h, const ushort_t* __restrict__ W1l,
    const float* __restrict__ b1,
    const ushort_t* __restrict__ W2h, const ushort_t* __restrict__ W2l,
    const float* __restrict__ b2,
    float* __restrict__ C,
    const float* __restrict__ uvb, float* __restrict__ v_io, float* __restrict__ s_io)
{
    constexpr int K1 = STACK ? 256 : 128;
    constexpr int ASZ = FIN ? 32 * 388 : 4;
    __shared__ __align__(16) ushort_t Ah[32 * 40], Al[32 * 40];
    __shared__ __align__(16) ushort_t Bh[128 * 40], Bl[128 * 40];
    __shared__ __align__(16) ushort_t Hh[32 * 136], Hl[32 * 136];
    __shared__ float Aa[ASZ];
    const int tid = threadIdx.x;
    const int wave = tid >> 6, lane = tid & 63;
    const int row_l = lane & 15, quad = lane >> 4;
    const int wn = wave * 32;
    const int m0 = blockIdx.x * 32;
    const int lrA = tid >> 3;          // 0..31
    const int ksA = (tid & 7) * 4;     // 0,4,..28
    const int lrB = tid >> 1, ksB = (tid & 1) * 16;

    // ---------- stage 1: h = silu(A @ W1 + b1) ----------
    f32x4 acc[2][2];
    #pragma unroll
    for (int i = 0; i < 2; ++i)
        #pragma unroll
        for (int j = 0; j < 2; ++j)
            #pragma unroll
            for (int r = 0; r < 4; ++r) acc[i][j][r] = 0.f;

    for (int k0 = 0; k0 < K1; k0 += 32) {
        float e[4];
        if (STACK == 0 || k0 + ksA < 128) {
            float4 v = *(const float4*)&sbuf[(size_t)(m0 + lrA) * 128 + k0 + ksA];
            e[0] = v.x; e[1] = v.y; e[2] = v.z; e[3] = v.w;
        } else {
            int f = k0 + ksA - 128;
            const float* px = &vvp[(size_t)(m0 + lrA) * 3 * F + f];
            float4 x = *(const float4*)px;
            float4 y = *(const float4*)(px + F);
            float4 z = *(const float4*)(px + 2 * F);
            e[0] = sqrtf(x.x*x.x + y.x*y.x + z.x*z.x + 1e-15f);
            e[1] = sqrtf(x.y*x.y + y.y*y.y + z.y*z.y + 1e-15f);
            e[2] = sqrtf(x.z*x.z + y.z*y.z + z.z*z.z + 1e-15f);
            e[3] = sqrtf(x.w*x.w + y.w*y.w + z.w*z.w + 1e-15f);
        }
        ushort_t ph[4], pl[4];
        #pragma unroll
        for (int t = 0; t < 4; ++t) {
            ushort_t h = f2bf(e[t]);
            ph[t] = h; pl[t] = f2bf(e[t] - bf2f(h));
        }
        *(uint2*)&Ah[lrA * 40 + ksA] = *(uint2*)ph;
        *(uint2*)&Al[lrA * 40 + ksA] = *(uint2*)pl;
        {
            const ushort_t* bh = &W1h[(size_t)lrB * K1 + k0 + ksB];
            const ushort_t* bl = &W1l[(size_t)lrB * K1 + k0 + ksB];
            *(uint4*)&Bh[lrB * 40 + ksB]     = *(const uint4*)bh;
            *(uint4*)&Bh[lrB * 40 + ksB + 8] = *(const uint4*)(bh + 8);
            *(uint4*)&Bl[lrB * 40 + ksB]     = *(const uint4*)bl;
            *(uint4*)&Bl[lrB * 40 + ksB + 8] = *(const uint4*)(bl + 8);
        }
        __syncthreads();
        bf16x8 ahf[2], alf[2], bhf[2], blf[2];
        #pragma unroll
        for (int i = 0; i < 2; ++i) {
            int ar = (i * 16 + row_l) * 40 + quad * 8;
            ahf[i] = *(const bf16x8*)&Ah[ar];
            alf[i] = *(const bf16x8*)&Al[ar];
        }
        #pragma unroll
        for (int j = 0; j < 2; ++j) {
            int br = (wn + j * 16 + row_l) * 40 + quad * 8;
            bhf[j] = *(const bf16x8*)&Bh[br];
            blf[j] = *(const bf16x8*)&Bl[br];
        }
        #pragma unroll
        for (int i = 0; i < 2; ++i)
            #pragma unroll
            for (int j = 0; j < 2; ++j) {
                acc[i][j] = __builtin_amdgcn_mfma_f32_16x16x32_bf16(ahf[i], bhf[j], acc[i][j], 0, 0, 0);
                acc[i][j] = __builtin_amdgcn_mfma_f32_16x16x32_bf16(ahf[i], blf[j], acc[i][j], 0, 0, 0);
                acc[i][j] = __builtin_amdgcn_mfma_f32_16x16x32_bf16(alf[i], bhf[j], acc[i][j], 0, 0, 0);
            }
        __syncthreads();
    }
    // epilogue 1 -> h in LDS (bf16 hi/lo, [row][k] stride 136)
    #pragma unroll
    for (int j = 0; j < 2; ++j) {
        int col = wn + j * 16 + row_l;
        float bval = b1[col];
        #pragma unroll
        for (int i = 0; i < 2; ++i)
            #pragma unroll
            for (int r = 0; r < 4; ++r) {
                int row = i * 16 + quad * 4 + r;
                float v = silu_f(acc[i][j][r] + bval);
                ushort_t h = f2bf(v);
                Hh[row * 136 + col] = h;
                Hl[row * 136 + col] = f2bf(v - bf2f(h));
            }
    }

    // ---------- stage 2: OUT = h @ W2 + b2 (3 column tiles of 128) ----------
    for (int ct = 0; ct < 3; ++ct) {
        #pragma unroll
        for (int i = 0; i < 2; ++i)
            #pragma unroll
            for (int j = 0; j < 2; ++j)
                #pragma unroll
                for (int r = 0; r < 4; ++r) acc[i][j][r] = 0.f;
        for (int k0 = 0; k0 < 128; k0 += 32) {
            {
                const ushort_t* bh = &W2h[(size_t)(ct * 128 + lrB) * 128 + k0 + ksB];
                const ushort_t* bl = &W2l[(size_t)(ct * 128 + lrB) * 128 + k0 + ksB];
                *(uint4*)&Bh[lrB * 40 + ksB]     = *(const uint4*)bh;
                *(uint4*)&Bh[lrB * 40 + ksB + 8] = *(const uint4*)(bh + 8);
                *(uint4*)&Bl[lrB * 40 + ksB]     = *(const uint4*)bl;
                *(uint4*)&Bl[lrB * 40 + ksB + 8] = *(const uint4*)(bl + 8);
            }
            __syncthreads();
            bf16x8 ahf[2], alf[2], bhf[2], blf[2];
            #pragma unroll
            for (int i = 0; i < 2; ++i) {
                int ar = (i * 16 + row_l) * 136 + k0 + quad * 8;
                ahf[i] = *(const bf16x8*)&Hh[ar];
                alf[i] = *(const bf16x8*)&Hl[ar];
            }
            #pragma unroll
            for (int j = 0; j < 2; ++j) {
                int br = (wn + j * 16 + row_l) * 40 + quad * 8;
                bhf[j] = *(const bf16x8*)&Bh[br];
                blf[j] = *(const bf16x8*)&Bl[br];
            }
            #pragma unroll
            for (int i = 0; i < 2; ++i)
                #pragma unroll
                for (int j = 0; j < 2; ++j) {
                    acc[i][j] = __builtin_amdgcn_mfma_f32_16x16x32_bf16(ahf[i], bhf[j], acc[i][j], 0, 0, 0);
                    acc[i][j] = __builtin_amdgcn_mfma_f32_16x16x32_bf16(ahf[i], blf[j], acc[i][j], 0, 0, 0);
                    acc[i][j] = __builtin_amdgcn_mfma_f32_16x16x32_bf16(alf[i], bhf[j], acc[i][j], 0, 0, 0);
                }
            __syncthreads();
        }
        #pragma unroll
        for (int j = 0; j < 2; ++j) {
            int col = ct * 128 + wn + j * 16 + row_l;
            float bval = b2[col];
            #pragma unroll
            for (int i = 0; i < 2; ++i)
                #pragma unroll
                for (int r = 0; r < 4; ++r) {
                    int row = i * 16 + quad * 4 + r;
                    float v = acc[i][j][r] + bval;
                    if constexpr (FIN) Aa[row * 388 + col] = v;
                    else C[(size_t)(m0 + row) * 384 + col] = v;
                }
        }
    }

    // ---------- inline finupd (FIN=1) ----------
    if constexpr (FIN) {
        __syncthreads();
        #pragma unroll 4
        for (int p = 0; p < 16; ++p) {
            int idx = p * 256 + tid;           // 0..4095
            int ln = idx >> 7, f = idx & 127;
            int n = m0 + ln;
            size_t vb = (size_t)n * 3 * F + f;
            float ux = uvb[vb], uy = uvb[vb + F], uz = uvb[vb + 2*F];
            float wx = vvp[vb], wy = vvp[vb + F], wz = vvp[vb + 2*F];
            float dot = ux*wx + uy*wy + uz*wz;
            s_io[(size_t)n * F + f] += dot * Aa[ln * 388 + 128 + f] + Aa[ln * 388 + 256 + f];
            float avv = Aa[ln * 388 + f];
            v_io[vb]        += ux * avv;
            v_io[vb + F]    += uy * avv;
            v_io[vb + 2*F]  += uz * avv;
        }
    }
}

// ---------------- atom-centric message gather (atomic-free, packed records) ----------------
// v layout: [n][3][f]. ZVIN=1: v_in is implicitly zero (conv 0) — skip reads.
template<int ZVIN>
__global__ __launch_bounds__(128) void msg_gather(
    const float* __restrict__ phi, const float* __restrict__ rec,
    const float* __restrict__ rbf_w, const float* __restrict__ rbf_b,
    const float* __restrict__ v_in, float* __restrict__ s,
    float* __restrict__ v_out, const int* __restrict__ offsets,
    const int* __restrict__ cnt)
{
    const int n = blockIdx.x, tid = threadIdx.x;
    float W0[N_RBF], W1[N_RBF], W2[N_RBF];
    #pragma unroll
    for (int k = 0; k < N_RBF; ++k) {
        W0[k] = rbf_w[k*3*F + tid];
        W1[k] = rbf_w[k*3*F + F + tid];
        W2[k] = rbf_w[k*3*F + 2*F + tid];
    }
    const float b0 = rbf_b[tid], b1 = rbf_b[F + tid], b2 = rbf_b[2*F + tid];
    float ds = 0.f, dvx = 0.f, dvy = 0.f, dvz = 0.f;
    const int off = offsets[n], c = cnt[n];
    const float* r = rec + (size_t)off * REC;
    #pragma unroll 2
    for (int t = 0; t < c; ++t, r += REC) {
        int j = __float_as_int(r[0]);
        float ev = r[1];
        float ux = r[2], uy = r[3], uz = r[4];
        float w0 = b0 * ev, w1 = b1 * ev, w2 = b2 * ev;
        #pragma unroll
        for (int k = 0; k < N_RBF; ++k) {
            float rk = r[5 + k];
            w0 += rk * W0[k]; w1 += rk * W1[k]; w2 += rk * W2[k];
        }
        const float* prow = phi + (size_t)j * 3 * F;
        float s0 = prow[tid] * w0;
        float s1 = prow[F + tid] * w1;
        float s2 = prow[2*F + tid] * w2;
        ds  += s1;
        if constexpr (ZVIN) {
            dvx += s2*ux; dvy += s2*uy; dvz += s2*uz;
        } else {
            const float* vrow = v_in + (size_t)j * 3 * F;
            dvx += s2*ux + s0 * vrow[tid];
            dvy += s2*uy + s0 * vrow[F + tid];
            dvz += s2*uz + s0 * vrow[2*F + tid];
        }
    }
    s[(size_t)n * F + tid] += ds;
    size_t vb = (size_t)n * 3 * F + tid;
    if constexpr (ZVIN) {
        v_out[vb]       = dvx;
        v_out[vb + F]   = dvy;
        v_out[vb + 2*F] = dvz;
    } else {
        v_out[vb]       = v_in[vb]       + dvx;
        v_out[vb + F]   = v_in[vb + F]   + dvy;
        v_out[vb + 2*F] = v_in[vb + 2*F] + dvz;
    }
}

// ---------------- readout reduce: atom_e = h2[n][0:64]·w2 + b2; LDS mol table ----------------
__global__ __launch_bounds__(256) void rreduce_kernel(
    const float* __restrict__ h2, const float* __restrict__ w2,
    const float* __restrict__ b2, const int* __restrict__ mol,
    float* __restrict__ out)
{
    __shared__ float molacc[128];
    int tid = threadIdx.x, wave = tid >> 6, lane = tid & 63;
    if (tid < 128) molacc[tid] = 0.f;
    float w2v = w2[lane], b2v = b2[0];
    int n0 = blockIdx.x * 250;
    __syncthreads();
    for (int t = wave; t < 250; t += 4) {
        int n = n0 + t;
        float val = h2[(size_t)n * 128 + lane] * w2v;
        #pragma unroll
        for (int o = 32; o > 0; o >>= 1) val += __shfl_down(val, o);
        if (lane == 0) atomicAdd(&molacc[mol[n]], val + b2v);
    }
    __syncthreads();
    int lo = mol[n0], hi = mol[n0 + 249];
    for (int m = lo + tid; m <= hi; m += 256)
        atomicAdd(&out[m], molacc[m]);
}

extern "C" void kernel_launch(void* const* d_in, const int* in_sizes, int n_in,
                              void* d_out, int out_size, void* d_ws, size_t ws_size,
                              hipStream_t stream)
{
    const float* xyz    = (const float*)d_in[0];
    const float* emb    = (const float*)d_in[1];
    const float* msg_w1 = (const float*)d_in[2];
    const float* msg_b1 = (const float*)d_in[3];
    const float* msg_w2 = (const float*)d_in[4];
    const float* msg_b2 = (const float*)d_in[5];
    const float* rbf_w  = (const float*)d_in[6];
    const float* rbf_b  = (const float*)d_in[7];
    const float* upd_u  = (const float*)d_in[8];
    const float* upd_v  = (const float*)d_in[9];
    const float* upd_w1 = (const float*)d_in[10];
    const float* upd_b1 = (const float*)d_in[11];
    const float* upd_w2 = (const float*)d_in[12];
    const float* upd_b2 = (const float*)d_in[13];
    const float* ro_w1  = (const float*)d_in[14];
    const float* ro_b1  = (const float*)d_in[15];
    const float* ro_w2  = (const float*)d_in[16];
    const float* ro_b2  = (const float*)d_in[17];
    const int*   z      = (const int*)d_in[18];
    const int*   nbrs   = (const int*)d_in[19];
    const int*   molidx = (const int*)d_in[20];
    float* out = (float*)d_out;

    float* ws = (float*)d_ws;
    size_t off = 0;
    auto alloc = [&](size_t n) { float* p = ws + off; off += n; return p; };
    float* s_buf   = alloc(NFC);
    float* v1_buf  = alloc(3 * NFC);       // [n][3][f]
    float* v2_buf  = alloc(3 * NFC);
    float* uv_buf  = alloc(3 * NFC);
    float* vv_buf  = alloc(3 * NFC);
    float* phi_buf = alloc(3 * NFC);       // phi / readout-hidden
    float* rbfe    = alloc((size_t)N_EDGES * N_RBF);
    float* envb    = alloc(N_EDGES);
    float* unitb   = alloc((size_t)N_EDGES * 3);
    float* edgerec = alloc((size_t)N_EDGES * REC);
    ushort_t* wbf_hi = (ushort_t*)alloc(WPREP_W / 2 + 64);
    ushort_t* wbf_lo = (ushort_t*)alloc(WPREP_W / 2 + 64);
    float* robias   = alloc(128);
    int* cnt        = (int*)alloc(N_ATOMS);
    int* cursor     = (int*)alloc(N_ATOMS);
    int* offsets    = (int*)alloc(N_ATOMS);

    // bf16 weight sub-offsets (elements, see wprep_kernel)
    const size_t oW1 = 0, oW2 = 49152, oUV = 196608, oU1 = 294912, oU2 = 393216, oRO = 540672;

    hipMemsetAsync(out, 0, sizeof(float) * N_MOLS, stream);
    hipMemsetAsync(cnt, 0, sizeof(int) * 2 * N_ATOMS, stream);   // cnt + cursor adjacent

    geom_kernel<<<dim3((N_EDGES + 255) / 256), dim3(256), 0, stream>>>(
        xyz, nbrs, rbfe, envb, unitb, cnt);
    scan_kernel<<<dim3(1), dim3(1024), 0, stream>>>(cnt, offsets);
    scatter_kernel<<<dim3((N_EDGES + 255) / 256), dim3(256), 0, stream>>>(
        nbrs, envb, rbfe, unitb, offsets, cursor, edgerec);
    embed_kernel<<<dim3(N_ATOMS * F / 256), dim3(256), 0, stream>>>(emb, z, s_buf);
    wprep_kernel<<<dim3((WPREP_TOTAL + 255) / 256), dim3(256), 0, stream>>>(
        msg_w1, msg_w2, upd_u, upd_v, upd_w1, upd_w2, ro_w1, ro_b1,
        wbf_hi, wbf_lo, robias);

    float* vin = v1_buf;
    float* vout = v2_buf;
    for (int i = 0; i < 3; ++i) {
        // phi = silu(s@W1+b1)@W2+b2 — fused, h stays in LDS (252 blocks)
        mlp2_kernel<0, 0><<<dim3(NP/32), dim3(256), 0, stream>>>(
            s_buf, nullptr,
            wbf_hi + oW1 + (size_t)i*16384, wbf_lo + oW1 + (size_t)i*16384,
            msg_b1 + (size_t)i*F,
            wbf_hi + oW2 + (size_t)i*49152, wbf_lo + oW2 + (size_t)i*49152,
            msg_b2 + (size_t)i*3*F,
            phi_buf, nullptr, nullptr, nullptr);
        // atomic-free message gather: s += ds in place; vout = vin + dv
        if (i == 0)
            msg_gather<1><<<dim3(N_ATOMS), dim3(128), 0, stream>>>(
                phi_buf, edgerec, rbf_w + (size_t)i*N_RBF*3*F, rbf_b + (size_t)i*3*F,
                vin, s_buf, vout, offsets, cnt);
        else
            msg_gather<0><<<dim3(N_ATOMS), dim3(128), 0, stream>>>(
                phi_buf, edgerec, rbf_w + (size_t)i*N_RBF*3*F, rbf_b + (size_t)i*3*F,
                vin, s_buf, vout, offsets, cnt);
        // fused u_v|v_v: one GEMM over M=3*NP rows ([n][3] row order), split-column (756 blocks)
        gemm64<64><<<dim3(2, 3*NP/64), dim3(256), 0, stream>>>(
            vout,
            wbf_hi + oUV + (size_t)i*32768, wbf_lo + oUV + (size_t)i*32768,
            nullptr, uv_buf, vv_buf,
            128, F, F, F, 0);
        // a = silu([s|norm(vv)]@W1+b1)@W2+b2 + inline finupd (252 blocks)
        mlp2_kernel<1, 1><<<dim3(NP/32), dim3(256), 0, stream>>>(
            s_buf, vv_buf,
            wbf_hi + oU1 + (size_t)i*32768, wbf_lo + oU1 + (size_t)i*32768,
            upd_b1 + (size_t)i*F,
            wbf_hi + oU2 + (size_t)i*49152, wbf_lo + oU2 + (size_t)i*49152,
            upd_b2 + (size_t)i*3*F,
            nullptr, uv_buf, vout, s_buf);
        float* tmp = vin; vin = vout; vout = tmp;
    }

    // readout: h2 = silu(s @ ro_w1pad + b1pad) via MFMA (252 blocks), then LDS-table reduce
    gemm64<32><<<dim3(1, NP/32), dim3(256), 0, stream>>>(
        s_buf,
        wbf_hi + oRO, wbf_lo + oRO,
        robias, phi_buf, phi_buf,
        128, 128, 128, 128, 1);
    rreduce_kernel<<<dim3(32), dim3(256), 0, stream>>>(
        phi_buf, ro_w2, ro_b2, molidx, out);
}